// Round 10
// baseline (258.740 us; speedup 1.0000x reference)
//
#include <hip/hip_runtime.h>
#include <math.h>

#define QN 8192
#define SN 32768
#define EN 131072
#define DN 256
#define HN 8
#define HDN 32
#define GEON 128
#define FFNN 512

typedef __attribute__((ext_vector_type(8))) short bf16x8;
typedef __attribute__((ext_vector_type(8))) unsigned short u16x8;
typedef __attribute__((ext_vector_type(4))) float f32x4;

__device__ __forceinline__ unsigned short f2b(float f) {
  union { float f; unsigned u; } v; v.f = f;
  unsigned u = v.u;
  u += 0x7fffu + ((u >> 16) & 1u);   // round-to-nearest-even
  return (unsigned short)(u >> 16);
}
__device__ __forceinline__ float b2f(unsigned short h) {
  union { unsigned u; float f; } v; v.u = ((unsigned)h) << 16; return v.f;
}
__device__ __forceinline__ float gelu_f(float x) {
  return 0.5f * x * (1.0f + erff(x * 0.70710678118654752440f));
}

// XOR swizzle in 8-element groups: phys_g = g ^ (row&7). Staging writes and
// fragment reads both land at the b128 minimum aliasing (conflict-free).
template <int KT>
__device__ __forceinline__ u16x8* lds_gk(unsigned short* base, int row, int col) {
  int g = (col >> 3) ^ (row & 7);
  return reinterpret_cast<u16x8*>(base + row * KT + g * 8);
}
// scalar u16 store into the same swizzled layout
__device__ __forceinline__ unsigned short* lds_gs128(unsigned short* base, int row, int col) {
  int g = (col >> 3) ^ (row & 7);
  return base + row * 128 + g * 8 + (col & 7);
}
__device__ __forceinline__ unsigned short* lds_gs512(unsigned short* base, int row, int col) {
  int g = (col >> 3) ^ (row & 7);
  return base + row * 512 + g * 8 + (col & 7);
}

// ================= L1: fused prep = transpose + seg_offsets + LN1 ==========
__global__ __launch_bounds__(256) void fused_prep(
    const float* Wq, const float* Wk, const float* Wv, const float* Wg,
    const float* Wo, const float* Wf1, const float* Wf2,
    unsigned short* WqT, unsigned short* WkvT, unsigned short* WgT,
    unsigned short* WoT, unsigned short* Wf1T, unsigned short* Wf2T,
    const int* q_idx, int* offs,
    const float* x_ln, const float* lng, const float* lnb, unsigned short* ln_out) {
  __shared__ float ts[64][65];
  int b = blockIdx.x;
  int t = threadIdx.x;
  if (b < 136) {
    const float* src; unsigned short* dst; int K, N, tile;
    if (b < 16)       { src = Wq;  dst = WqT;          K = 256; N = 256; tile = b; }
    else if (b < 32)  { src = Wk;  dst = WkvT;         K = 256; N = 256; tile = b - 16; }
    else if (b < 48)  { src = Wv;  dst = WkvT + 65536; K = 256; N = 256; tile = b - 32; }
    else if (b < 56)  { src = Wg;  dst = WgT;          K = 128; N = 256; tile = b - 48; }
    else if (b < 72)  { src = Wo;  dst = WoT;          K = 256; N = 256; tile = b - 56; }
    else if (b < 104) { src = Wf1; dst = Wf1T;         K = 256; N = 512; tile = b - 72; }
    else              { src = Wf2; dst = Wf2T;         K = 512; N = 256; tile = b - 104; }
    int ktiles = K >> 6;
    int k0 = (tile % ktiles) * 64, n0 = (tile / ktiles) * 64;
    int c4 = (t & 15) * 4;
    int r = t >> 4;
#pragma unroll
    for (int p = 0; p < 4; ++p) {
      int row = p * 16 + r;
      float4 v = *(const float4*)(src + (size_t)(k0 + row) * N + n0 + c4);
      ts[row][c4 + 0] = v.x; ts[row][c4 + 1] = v.y;
      ts[row][c4 + 2] = v.z; ts[row][c4 + 3] = v.w;
    }
    __syncthreads();
#pragma unroll
    for (int p = 0; p < 4; ++p) {
      int n = p * 16 + r;
      ushort4 o;
      o.x = f2b(ts[c4 + 0][n]); o.y = f2b(ts[c4 + 1][n]);
      o.z = f2b(ts[c4 + 2][n]); o.w = f2b(ts[c4 + 3][n]);
      *(ushort4*)(dst + (size_t)(n0 + n) * K + k0 + c4) = o;
    }
  } else if (b < 169) {
    int i = (b - 136) * 256 + t;
    if (i > QN) return;
    int lo = 0, hi = EN;
    while (lo < hi) {
      int mid = (lo + hi) >> 1;
      if (q_idx[mid] < i) lo = mid + 1; else hi = mid;
    }
    offs[i] = lo;
  } else {
    int row = (b - 169) * 4 + (t >> 6);
    int lane = t & 63;
    const float* xr = x_ln + (size_t)row * DN;
    float4 v = *(const float4*)(xr + lane * 4);
    float s = v.x + v.y + v.z + v.w;
    float ss = v.x * v.x + v.y * v.y + v.z * v.z + v.w * v.w;
#pragma unroll
    for (int msk = 1; msk <= 32; msk <<= 1) {
      s += __shfl_xor(s, msk);
      ss += __shfl_xor(ss, msk);
    }
    float mean = s * (1.f / 256.f);
    float var = ss * (1.f / 256.f) - mean * mean;
    float rs = 1.0f / sqrtf(var + 1e-5f);
    float4 gg = *(const float4*)(lng + lane * 4);
    float4 bb = *(const float4*)(lnb + lane * 4);
    unsigned short* o = ln_out + (size_t)row * DN + lane * 4;
    o[0] = f2b((v.x - mean) * rs * gg.x + bb.x);
    o[1] = f2b((v.y - mean) * rs * gg.y + bb.y);
    o[2] = f2b((v.z - mean) * rs * gg.z + bb.z);
    o[3] = f2b((v.w - mean) * rs * gg.w + bb.w);
  }
}

// ---------------- standalone LN (for LN2) ----------------
__global__ __launch_bounds__(256) void ln_kernel(
    const float* x, const float* g, const float* b, unsigned short* out) {
  int row = blockIdx.x * 4 + (threadIdx.x >> 6);
  int lane = threadIdx.x & 63;
  const float* xr = x + (size_t)row * DN;
  float4 v = *(const float4*)(xr + lane * 4);
  float s = v.x + v.y + v.z + v.w;
  float ss = v.x * v.x + v.y * v.y + v.z * v.z + v.w * v.w;
#pragma unroll
  for (int msk = 1; msk <= 32; msk <<= 1) {
    s += __shfl_xor(s, msk);
    ss += __shfl_xor(ss, msk);
  }
  float mean = s * (1.f / 256.f);
  float var = ss * (1.f / 256.f) - mean * mean;
  float rs = 1.0f / sqrtf(var + 1e-5f);
  float4 gg = *(const float4*)(g + lane * 4);
  float4 bb = *(const float4*)(b + lane * 4);
  unsigned short* o = out + (size_t)row * DN + lane * 4;
  o[0] = f2b((v.x - mean) * rs * gg.x + bb.x);
  o[1] = f2b((v.y - mean) * rs * gg.y + bb.y);
  o[2] = f2b((v.z - mean) * rs * gg.z + bb.z);
  o[3] = f2b((v.w - mean) * rs * gg.w + bb.w);
}

// ================= device bodies for fused stage 2 (R5/R9-proven) ==========

// ---- KV GEMM body ----
__device__ __forceinline__ void kv_body(
    char* smem, const float* A, const unsigned short* BT, unsigned short* KVb,
    int bm, int t) {
  unsigned short* As = (unsigned short*)smem;            // 32 KB
  unsigned short* Bs = (unsigned short*)(smem + 32768);  // 16 KB
  int w = t >> 6, lane = t & 63;
  int quad = lane >> 4, l16 = lane & 15;
  int wr = w >> 1, wc = w & 1;
  {
    int prow = t >> 6;
    int c4 = (t & 63) * 4;
#pragma unroll
    for (int p = 0; p < 16; ++p) {
      int lr = p * 4 + prow;
      float4 f = *(const float4*)(A + (size_t)(bm + lr) * 256 + c4);
      ushort4 u;
      u.x = f2b(f.x); u.y = f2b(f.y); u.z = f2b(f.z); u.w = f2b(f.w);
      int g = (c4 >> 3) ^ (lr & 7);
      *(ushort4*)(As + lr * 256 + g * 8 + (c4 & 7)) = u;
    }
  }
  int brow = t >> 3, bsub = t & 7;
  u16x8 pre[4];
  {
    const unsigned short* Bg = BT + (size_t)brow * 256 + bsub * 32;
#pragma unroll
    for (int i = 0; i < 4; ++i) pre[i] = *reinterpret_cast<const u16x8*>(Bg + i * 8);
  }
  for (int ct = 0; ct < 16; ++ct) {
#pragma unroll
    for (int i = 0; i < 4; ++i)
      *lds_gk<256>(Bs, brow, bsub * 32 + i * 8) = pre[i];
    __syncthreads();
    if (ct < 15) {
      const unsigned short* Bg = BT + (size_t)((ct + 1) * 32 + brow) * 256 + bsub * 32;
#pragma unroll
      for (int i = 0; i < 4; ++i) pre[i] = *reinterpret_cast<const u16x8*>(Bg + i * 8);
    }
    f32x4 acc[2];
    acc[0] = (f32x4){0.f, 0.f, 0.f, 0.f};
    acc[1] = (f32x4){0.f, 0.f, 0.f, 0.f};
#pragma unroll
    for (int k = 0; k < 8; ++k) {
      bf16x8 a0 = *reinterpret_cast<bf16x8*>(lds_gk<256>(As, wr * 32 + l16, k * 32 + quad * 8));
      bf16x8 a1 = *reinterpret_cast<bf16x8*>(lds_gk<256>(As, wr * 32 + 16 + l16, k * 32 + quad * 8));
      bf16x8 b0 = *reinterpret_cast<bf16x8*>(lds_gk<256>(Bs, wc * 16 + l16, k * 32 + quad * 8));
      acc[0] = __builtin_amdgcn_mfma_f32_16x16x32_bf16(a0, b0, acc[0], 0, 0, 0);
      acc[1] = __builtin_amdgcn_mfma_f32_16x16x32_bf16(a1, b0, acc[1], 0, 0, 0);
    }
#pragma unroll
    for (int i = 0; i < 2; ++i)
#pragma unroll
      for (int r = 0; r < 4; ++r) {
        int rw = bm + wr * 32 + i * 16 + quad * 4 + r;
        int col = ct * 32 + wc * 16 + l16;
        KVb[(size_t)rw * 512 + col] = f2b(acc[i][r]);
      }
    __syncthreads();
  }
}

// ---- gemm64 body: 64x64 tile, 10.2KB LDS, k-step register prefetch --------
template <bool A_FP32, bool HAS_BIAS, bool DO_GELU, bool HAS_RESID, bool STORE_F32>
__device__ __forceinline__ void gemm64_body(
    char* smem, const void* Ap, const unsigned short* BT, int N, int K,
    const float* bias, const float* resid, float* outF, unsigned short* outB,
    int bm, int bn, int t) {
  unsigned short (*As)[40] = (unsigned short(*)[40])smem;
  unsigned short (*Bs)[40] = (unsigned short(*)[40])(smem + 5120);
  int w = t >> 6, lane = t & 63;
  int wr = w >> 1, wc = w & 1;
  int quad = lane >> 4, l16 = lane & 15;
  int row = t >> 2, chunk = t & 3;

  const float* AgF = (const float*)Ap + (size_t)(bm + row) * K + chunk * 8;
  const unsigned short* AgB = (const unsigned short*)Ap + (size_t)(bm + row) * K + chunk * 8;
  const unsigned short* Bg = BT + (size_t)(bn + row) * K + chunk * 8;

  float4 pf0, pf1;
  u16x8 pa, pb;
  if (A_FP32) { pf0 = *(const float4*)AgF; pf1 = *(const float4*)(AgF + 4); }
  else        { pa = *(const u16x8*)AgB; }
  pb = *(const u16x8*)Bg;

  f32x4 acc[2][2];
#pragma unroll
  for (int i = 0; i < 2; ++i)
#pragma unroll
    for (int j = 0; j < 2; ++j) acc[i][j] = (f32x4){0.f, 0.f, 0.f, 0.f};

  for (int k0 = 0; k0 < K; k0 += 32) {
    u16x8 ua;
    if (A_FP32) {
      ua[0] = f2b(pf0.x); ua[1] = f2b(pf0.y); ua[2] = f2b(pf0.z); ua[3] = f2b(pf0.w);
      ua[4] = f2b(pf1.x); ua[5] = f2b(pf1.y); ua[6] = f2b(pf1.z); ua[7] = f2b(pf1.w);
    } else {
      ua = pa;
    }
    *reinterpret_cast<u16x8*>(&As[row][chunk * 8]) = ua;
    *reinterpret_cast<u16x8*>(&Bs[row][chunk * 8]) = pb;
    __syncthreads();
    if (k0 + 32 < K) {
      if (A_FP32) { pf0 = *(const float4*)(AgF + k0 + 32); pf1 = *(const float4*)(AgF + k0 + 36); }
      else        { pa = *(const u16x8*)(AgB + k0 + 32); }
      pb = *(const u16x8*)(Bg + k0 + 32);
    }
    bf16x8 a0 = *reinterpret_cast<const bf16x8*>(&As[wr * 32 + l16][quad * 8]);
    bf16x8 a1 = *reinterpret_cast<const bf16x8*>(&As[wr * 32 + 16 + l16][quad * 8]);
    bf16x8 b0 = *reinterpret_cast<const bf16x8*>(&Bs[wc * 32 + l16][quad * 8]);
    bf16x8 b1 = *reinterpret_cast<const bf16x8*>(&Bs[wc * 32 + 16 + l16][quad * 8]);
    acc[0][0] = __builtin_amdgcn_mfma_f32_16x16x32_bf16(a0, b0, acc[0][0], 0, 0, 0);
    acc[0][1] = __builtin_amdgcn_mfma_f32_16x16x32_bf16(a0, b1, acc[0][1], 0, 0, 0);
    acc[1][0] = __builtin_amdgcn_mfma_f32_16x16x32_bf16(a1, b0, acc[1][0], 0, 0, 0);
    acc[1][1] = __builtin_amdgcn_mfma_f32_16x16x32_bf16(a1, b1, acc[1][1], 0, 0, 0);
    __syncthreads();
  }

#pragma unroll
  for (int i = 0; i < 2; ++i)
#pragma unroll
    for (int j = 0; j < 2; ++j) {
      int col = bn + wc * 32 + j * 16 + l16;
      float bv = HAS_BIAS ? bias[col] : 0.f;
#pragma unroll
      for (int r = 0; r < 4; ++r) {
        int rw = bm + wr * 32 + i * 16 + quad * 4 + r;
        float v = acc[i][j][r] + bv;
        if (DO_GELU) v = gelu_f(v);
        if (HAS_RESID) v += resid[(size_t)rw * N + col];
        if (STORE_F32) outF[(size_t)rw * N + col] = v;
        else outB[(size_t)rw * N + col] = f2b(v);
      }
    }
}

// ---- geo mega body (R5/R9-proven) ----
__device__ __forceinline__ void geo_body(
    char* smem, const float* qpos, const float* spos, const int* offs,
    const int* s_idx, const float* Gw1, const float* Gb1,
    const float* Gw2, const float* Gb2, const unsigned short* WgT,
    unsigned short* Gf_b, int qb, int t) {
  float (*rs)[12] = (float(*)[12])smem;
  unsigned short* geoL = (unsigned short*)(smem + 3072);
  float (*h1)[128] = (float(*)[128])(smem + 19456);
  unsigned short* Bs = (unsigned short*)(smem + 19456);

  {
    int q = qb + (t >> 2);
    int sub = t & 3;
    int e0 = offs[q], e1 = offs[q + 1];
    float qx = qpos[q * 3 + 0], qy = qpos[q * 3 + 1], qz = qpos[q * 3 + 2];
    float cnt = 0.f, sx = 0.f, sy = 0.f, sz = 0.f, sxx = 0.f, syy = 0.f, szz = 0.f;
    float mnx = 1e30f, mny = 1e30f, mnz = 1e30f, mxx = -1e30f, mxy = -1e30f, mxz = -1e30f;
    for (int e = e0 + sub; e < e1; e += 4) {
      int s = s_idx[e];
      float rx = spos[s * 3 + 0] - qx;
      float ry = spos[s * 3 + 1] - qy;
      float rz = spos[s * 3 + 2] - qz;
      cnt += 1.f;
      sx += rx; sy += ry; sz += rz;
      sxx += rx * rx; syy += ry * ry; szz += rz * rz;
      mnx = fminf(mnx, rx); mny = fminf(mny, ry); mnz = fminf(mnz, rz);
      mxx = fmaxf(mxx, rx); mxy = fmaxf(mxy, ry); mxz = fmaxf(mxz, rz);
    }
#pragma unroll
    for (int msk = 1; msk <= 2; msk <<= 1) {
      cnt += __shfl_xor(cnt, msk);
      sx += __shfl_xor(sx, msk); sy += __shfl_xor(sy, msk); sz += __shfl_xor(sz, msk);
      sxx += __shfl_xor(sxx, msk); syy += __shfl_xor(syy, msk); szz += __shfl_xor(szz, msk);
      mnx = fminf(mnx, __shfl_xor(mnx, msk));
      mny = fminf(mny, __shfl_xor(mny, msk));
      mnz = fminf(mnz, __shfl_xor(mnz, msk));
      mxx = fmaxf(mxx, __shfl_xor(mxx, msk));
      mxy = fmaxf(mxy, __shfl_xor(mxy, msk));
      mxz = fmaxf(mxz, __shfl_xor(mxz, msk));
    }
    if (sub == 0) {
      int qq = t >> 2;
      float c = fmaxf(cnt, 1.f);
      float mx_ = sx / c, my_ = sy / c, mz_ = sz / c;
      float vx = fmaxf(sxx / c - mx_ * mx_, 0.f);
      float vy = fmaxf(syy / c - my_ * my_, 0.f);
      float vz = fmaxf(szz / c - mz_ * mz_, 0.f);
      rs[qq][0] = mx_; rs[qq][1] = my_; rs[qq][2] = mz_;
      rs[qq][3] = sqrtf(vx); rs[qq][4] = sqrtf(vy); rs[qq][5] = sqrtf(vz);
      rs[qq][6] = fminf(fmaxf(mnx, -100.f), 100.f);
      rs[qq][7] = fminf(fmaxf(mny, -100.f), 100.f);
      rs[qq][8] = fminf(fmaxf(mnz, -100.f), 100.f);
      rs[qq][9] = fminf(fmaxf(mxx, -100.f), 100.f);
      rs[qq][10] = fminf(fmaxf(mxy, -100.f), 100.f);
      rs[qq][11] = fminf(fmaxf(mxz, -100.f), 100.f);
    }
  }
  __syncthreads();

  {
    int j = t & 127;
    int grp = t >> 7;
    int qbase = grp * 32;
    float acc[32];
    float b1 = Gb1[j];
#pragma unroll
    for (int qq = 0; qq < 32; ++qq) acc[qq] = b1;
    for (int i = 0; i < 12; ++i) {
      float wv = Gw1[i * GEON + j];
#pragma unroll
      for (int qq = 0; qq < 32; ++qq) acc[qq] += rs[qbase + qq][i] * wv;
    }
#pragma unroll
    for (int qq = 0; qq < 32; ++qq) h1[qbase + qq][j] = gelu_f(acc[qq]);
    __syncthreads();
    float b2 = Gb2[j];
    float acc2[32];
#pragma unroll
    for (int qq = 0; qq < 32; ++qq) acc2[qq] = b2;
    for (int k = 0; k < 128; ++k) {
      float wv = Gw2[k * GEON + j];
#pragma unroll
      for (int qq = 0; qq < 32; ++qq) acc2[qq] += h1[qbase + qq][k] * wv;
    }
#pragma unroll
    for (int qq = 0; qq < 32; ++qq)
      *lds_gs128(geoL, qbase + qq, j) = f2b(gelu_f(acc2[qq]));
  }
  __syncthreads();

  {
    int w = t >> 6, lane = t & 63;
    int wr = w >> 1, wc = w & 1;
    int quad = lane >> 4, l16 = lane & 15;
    int row = t >> 2, sub = t & 3;
    for (int ct = 0; ct < 4; ++ct) {
      int bn = ct * 64;
      {
        const unsigned short* Bg = WgT + (size_t)(bn + row) * 128 + sub * 32;
#pragma unroll
        for (int i = 0; i < 4; ++i)
          *lds_gk<128>(Bs, row, sub * 32 + i * 8) = *reinterpret_cast<const u16x8*>(Bg + i * 8);
      }
      __syncthreads();
      f32x4 acc[2][2];
#pragma unroll
      for (int i = 0; i < 2; ++i)
#pragma unroll
        for (int j = 0; j < 2; ++j) acc[i][j] = (f32x4){0.f, 0.f, 0.f, 0.f};
#pragma unroll
      for (int k = 0; k < 4; ++k) {
        bf16x8 a0 = *reinterpret_cast<bf16x8*>(lds_gk<128>(geoL, wr * 32 + l16, k * 32 + quad * 8));
        bf16x8 a1 = *reinterpret_cast<bf16x8*>(lds_gk<128>(geoL, wr * 32 + 16 + l16, k * 32 + quad * 8));
        bf16x8 b0 = *reinterpret_cast<bf16x8*>(lds_gk<128>(Bs, wc * 32 + l16, k * 32 + quad * 8));
        bf16x8 b1 = *reinterpret_cast<bf16x8*>(lds_gk<128>(Bs, wc * 32 + 16 + l16, k * 32 + quad * 8));
        acc[0][0] = __builtin_amdgcn_mfma_f32_16x16x32_bf16(a0, b0, acc[0][0], 0, 0, 0);
        acc[0][1] = __builtin_amdgcn_mfma_f32_16x16x32_bf16(a0, b1, acc[0][1], 0, 0, 0);
        acc[1][0] = __builtin_amdgcn_mfma_f32_16x16x32_bf16(a1, b0, acc[1][0], 0, 0, 0);
        acc[1][1] = __builtin_amdgcn_mfma_f32_16x16x32_bf16(a1, b1, acc[1][1], 0, 0, 0);
      }
#pragma unroll
      for (int i = 0; i < 2; ++i)
#pragma unroll
        for (int j = 0; j < 2; ++j) {
          int col = bn + wc * 32 + j * 16 + l16;
#pragma unroll
          for (int r = 0; r < 4; ++r) {
            int rw = qb + wr * 32 + i * 16 + quad * 4 + r;
            Gf_b[(size_t)rw * 256 + col] = f2b(acc[i][j][r]);
          }
        }
      __syncthreads();
    }
  }
}

// ================= L2: fused stage 2 = geo-mega + kv + Qf ==================
__global__ __launch_bounds__(256) void fused_stage2(
    const float* qpos, const float* spos, const int* offs, const int* s_idx,
    const float* Gw1, const float* Gb1, const float* Gw2, const float* Gb2,
    const unsigned short* WgT, unsigned short* Gf_b,
    const float* support_feats, const unsigned short* WkvT, unsigned short* KVb,
    const unsigned short* qt_b, const unsigned short* WqT, unsigned short* Qb) {
  __shared__ __align__(16) char smem[52224];
  int b = blockIdx.x;
  int t = threadIdx.x;
  if (b < 128) {
    geo_body(smem, qpos, spos, offs, s_idx, Gw1, Gb1, Gw2, Gb2, WgT, Gf_b, b * 64, t);
  } else if (b < 640) {
    kv_body(smem, support_feats, WkvT, KVb, (b - 128) * 64, t);
  } else {
    int bb = b - 640;
    int bm = (bb & 127) * 64, bn = (bb >> 7) * 64;
    gemm64_body<false, false, false, false, false>(
        smem, qt_b, WqT, DN, 256, nullptr, nullptr, nullptr, Qb, bm, bn, t);
  }
}

// ---------------- standalone gemm64 wrapper (Wo) ---------------
template <bool A_FP32, bool HAS_BIAS, bool DO_GELU, bool HAS_RESID, bool STORE_F32>
__global__ __launch_bounds__(256) void gemm64(
    const void* Ap, const unsigned short* BT, int N, int K,
    const float* bias, const float* resid, float* outF, unsigned short* outB) {
  __shared__ __align__(16) char smem[10240];
  gemm64_body<A_FP32, HAS_BIAS, DO_GELU, HAS_RESID, STORE_F32>(
      smem, Ap, BT, N, K, bias, resid, outF, outB,
      blockIdx.x * 64, blockIdx.y * 64, threadIdx.x);
}

// ================= fused FFN: out = gelu(z@Wf1+bf1)@Wf2 + bf2 + x1 =========
// 16-row blocks (512 blocks, 2 resident/CU at 24KB LDS). h kept in LDS bf16
// (same f2b rounding point as the old h_b path -> identical numerics).
// Saves the 16MB h_b round-trip + one launch.
__global__ __launch_bounds__(256) void ffn_kernel(
    const unsigned short* z_b, const unsigned short* Wf1T, const float* bf1,
    const unsigned short* Wf2T, const float* bf2, const float* x1, float* out) {
  __shared__ __align__(16) char smem[8192 + 16384];
  unsigned short* Zs = (unsigned short*)smem;           // [16][256] swizzled
  unsigned short* Hs = (unsigned short*)(smem + 8192);  // [16][512] swizzled
  int t = threadIdx.x;
  int bm = blockIdx.x * 16;
  int w = t >> 6, lane = t & 63;
  int quad = lane >> 4, l16 = lane & 15;
  // stage z: 16 rows x 256, 16 threads/row x 16 cols
  {
    int row = t >> 4, sub = t & 15;
    const unsigned short* Zg = z_b + (size_t)(bm + row) * 256 + sub * 16;
    *lds_gk<256>(Zs, row, sub * 16) = *(const u16x8*)Zg;
    *lds_gk<256>(Zs, row, sub * 16 + 8) = *(const u16x8*)(Zg + 8);
  }
  __syncthreads();
  // h = gelu(z @ Wf1 + bf1): wave w covers cols [w*128, w*128+128)
#pragma unroll
  for (int tile = 0; tile < 2; ++tile) {
    int cb = w * 128 + tile * 64;
    f32x4 acc[4];
#pragma unroll
    for (int j = 0; j < 4; ++j) acc[j] = (f32x4){0.f, 0.f, 0.f, 0.f};
#pragma unroll
    for (int k = 0; k < 8; ++k) {
      bf16x8 a = *reinterpret_cast<bf16x8*>(lds_gk<256>(Zs, l16, k * 32 + quad * 8));
#pragma unroll
      for (int j = 0; j < 4; ++j) {
        bf16x8 b = *reinterpret_cast<const bf16x8*>(
            Wf1T + (size_t)(cb + j * 16 + l16) * 256 + k * 32 + quad * 8);
        acc[j] = __builtin_amdgcn_mfma_f32_16x16x32_bf16(a, b, acc[j], 0, 0, 0);
      }
    }
#pragma unroll
    for (int j = 0; j < 4; ++j) {
      int col = cb + j * 16 + l16;
      float bv = bf1[col];
#pragma unroll
      for (int r = 0; r < 4; ++r) {
        int row = quad * 4 + r;
        *lds_gs512(Hs, row, col) = f2b(gelu_f(acc[j][r] + bv));
      }
    }
  }
  __syncthreads();
  // out = h @ Wf2 + bf2 + x1: wave w covers cols [w*64, w*64+64)
  {
    int cb = w * 64;
    f32x4 acc[4];
#pragma unroll
    for (int j = 0; j < 4; ++j) acc[j] = (f32x4){0.f, 0.f, 0.f, 0.f};
#pragma unroll
    for (int k = 0; k < 16; ++k) {
      bf16x8 a = *reinterpret_cast<bf16x8*>(lds_gk<512>(Hs, l16, k * 32 + quad * 8));
#pragma unroll
      for (int j = 0; j < 4; ++j) {
        bf16x8 b = *reinterpret_cast<const bf16x8*>(
            Wf2T + (size_t)(cb + j * 16 + l16) * 512 + k * 32 + quad * 8);
        acc[j] = __builtin_amdgcn_mfma_f32_16x16x32_bf16(a, b, acc[j], 0, 0, 0);
      }
    }
#pragma unroll
    for (int j = 0; j < 4; ++j) {
      int col = cb + j * 16 + l16;
      float bv = bf2[col];
#pragma unroll
      for (int r = 0; r < 4; ++r) {
        int rw = bm + quad * 4 + r;
        out[(size_t)rw * 256 + col] = acc[j][r] + bv + x1[(size_t)rw * 256 + col];
      }
    }
  }
}

// ---------------- edge attention: 4 edges/iter, 2-deep software pipeline ----
// s_idx preloaded one group ahead; K/V rows prefetched one iteration ahead
// (kv_gemm's proven pattern) -> the serial {s_idx -> K/V -> compute} chain
// is off the critical path. Arithmetic identical to R9.
__global__ __launch_bounds__(256) void attn_edge_kernel(
    const unsigned short* Qb, const unsigned short* Gfb, const unsigned short* KVb,
    const int* s_idx, const int* offs, const float* log_tau, unsigned short* attn_b) {
  int q = blockIdx.x * 4 + (threadIdx.x >> 6);
  int lane = threadIdx.x & 63;
  int slot = lane >> 4;
  int sl = lane & 15;
  int d0 = sl * 16;
  int e0 = offs[q], e1 = offs[q + 1];
  float invs = expf(-log_tau[0]) * 0.17677669529663687f;  // 1/(sqrt(32)*tau)
  u16x8 qu0 = *(const u16x8*)(Qb + (size_t)q * DN + d0);
  u16x8 qu1 = *(const u16x8*)(Qb + (size_t)q * DN + d0 + 8);
  u16x8 gu0 = *(const u16x8*)(Gfb + (size_t)q * DN + d0);
  u16x8 gu1 = *(const u16x8*)(Gfb + (size_t)q * DN + d0 + 8);
  float qf[16], gf[16];
#pragma unroll
  for (int j = 0; j < 8; ++j) {
    qf[j] = b2f(qu0[j]) * invs; qf[j + 8] = b2f(qu1[j]) * invs;
    gf[j] = b2f(gu0[j]);        gf[j + 8] = b2f(gu1[j]);
  }
  const float NEG = -1e30f;
  float m = -INFINITY, l = 0.f;
  float a[16];
#pragma unroll
  for (int j = 0; j < 16; ++j) a[j] = 0.f;

  int sNxt = 0;
  u16x8 cku0, cku1, cvu0, cvu1;
  if (e0 < e1) {
    int i0 = e0 + slot; if (i0 > e1 - 1) i0 = e1 - 1;
    int sCur = s_idx[i0];
    if (e0 + 4 < e1) { int i1 = e0 + 4 + slot; if (i1 > e1 - 1) i1 = e1 - 1; sNxt = s_idx[i1]; }
    const unsigned short* kr = KVb + (size_t)sCur * 512 + d0;
    cku0 = *(const u16x8*)kr;        cku1 = *(const u16x8*)(kr + 8);
    cvu0 = *(const u16x8*)(kr + 256); cvu1 = *(const u16x8*)(kr + 264);
  }
  for (int e = e0; e < e1; e += 4) {
    bool hasNext = (e + 4 < e1);
    u16x8 nku0, nku1, nvu0, nvu1;
    if (hasNext) {   // issue next iteration's K/V loads; latency hides under compute
      const unsigned short* krn = KVb + (size_t)sNxt * 512 + d0;
      nku0 = *(const u16x8*)krn;        nku1 = *(const u16x8*)(krn + 8);
      nvu0 = *(const u16x8*)(krn + 256); nvu1 = *(const u16x8*)(krn + 264);
      if (e + 8 < e1) { int i2 = e + 8 + slot; if (i2 > e1 - 1) i2 = e1 - 1; sNxt = s_idx[i2]; }
    }
    bool valid = (e + slot) < e1;
    float p = 0.f;
#pragma unroll
    for (int j = 0; j < 8; ++j) {
      p += qf[j] * b2f(cku0[j]);
      p += qf[j + 8] * b2f(cku1[j]);
    }
    p += __shfl_xor(p, 1);
    if (!valid) p = -INFINITY;
    float mnew = fmaxf(m, p);
    float sc = (m > NEG) ? __expf(m - mnew) : 0.f;
    float we = valid ? __expf(p - mnew) : 0.f;
    l = l * sc + we;
#pragma unroll
    for (int j = 0; j < 8; ++j) {
      a[j] = a[j] * sc + we * b2f(cvu0[j]);
      a[j + 8] = a[j + 8] * sc + we * b2f(cvu1[j]);
    }
    m = mnew;
    if (hasNext) { cku0 = nku0; cku1 = nku1; cvu0 = nvu0; cvu1 = nvu1; }
  }
#pragma unroll
  for (int msk = 16; msk <= 32; msk <<= 1) {
    float om = __shfl_xor(m, msk);
    float ol = __shfl_xor(l, msk);
    float M2 = fmaxf(m, om);
    float ws = (m > NEG) ? __expf(m - M2) : 0.f;
    float wo = (om > NEG) ? __expf(om - M2) : 0.f;
    l = l * ws + ol * wo;
#pragma unroll
    for (int j = 0; j < 16; ++j) {
      float oa = __shfl_xor(a[j], msk);
      a[j] = a[j] * ws + oa * wo;
    }
    m = M2;
  }
  float M = fmaxf(m, 0.f);
  float em = (m > NEG) ? __expf(m - M) : 0.f;
  float denom = fmaxf(l * em, 1e-8f);
  float f = em / denom;
  float sa = l * f;              // = sum(alpha)
  if (slot == 0) {
    u16x8 o0, o1;
#pragma unroll
    for (int j = 0; j < 8; ++j) {
      o0[j] = f2b(a[j] * f + gf[j] * sa);
      o1[j] = f2b(a[j + 8] * f + gf[j + 8] * sa);
    }
    *(u16x8*)(attn_b + (size_t)q * DN + d0) = o0;
    *(u16x8*)(attn_b + (size_t)q * DN + d0 + 8) = o1;
  }
}

extern "C" void kernel_launch(void* const* d_in, const int* in_sizes, int n_in,
                              void* d_out, int out_size, void* d_ws, size_t ws_size,
                              hipStream_t stream) {
  const float* query_tokens  = (const float*)d_in[0];
  const float* query_pos     = (const float*)d_in[1];
  const float* support_feats = (const float*)d_in[2];
  const float* support_pos   = (const float*)d_in[3];
  const float* Wq  = (const float*)d_in[4];
  const float* Wk  = (const float*)d_in[5];
  const float* Wv  = (const float*)d_in[6];
  const float* Wg  = (const float*)d_in[7];
  const float* Wo  = (const float*)d_in[8];
  const float* bo  = (const float*)d_in[9];
  const float* log_tau = (const float*)d_in[10];
  const float* ln1_g = (const float*)d_in[11];
  const float* ln1_b = (const float*)d_in[12];
  const float* ln2_g = (const float*)d_in[13];
  const float* ln2_b = (const float*)d_in[14];
  const float* Wf1 = (const float*)d_in[15];
  const float* bf1 = (const float*)d_in[16];
  const float* Wf2 = (const float*)d_in[17];
  const float* bf2 = (const float*)d_in[18];
  const float* Gw1 = (const float*)d_in[19];
  const float* Gb1 = (const float*)d_in[20];
  const float* Gw2 = (const float*)d_in[21];
  const float* Gb2 = (const float*)d_in[22];
  const int* q_idx = (const int*)d_in[23];
  const int* s_idx = (const int*)d_in[24];
  float* out = (float*)d_out;

  char* ws = (char*)d_ws;
  size_t off = 0;
  auto alloc = [&](size_t bytes) -> void* {
    void* p = ws + off;
    off = (off + bytes + 255) & ~(size_t)255;
    return p;
  };
  unsigned short* WqT  = (unsigned short*)alloc(65536 * 2);
  unsigned short* WkvT = (unsigned short*)alloc(131072 * 2);
  unsigned short* WgT  = (unsigned short*)alloc(32768 * 2);
  unsigned short* WoT  = (unsigned short*)alloc(65536 * 2);
  unsigned short* Wf1T = (unsigned short*)alloc(131072 * 2);
  unsigned short* Wf2T = (unsigned short*)alloc(131072 * 2);
  int* offs            = (int*)alloc((QN + 1) * 4);
  unsigned short* qt_b  = (unsigned short*)alloc((size_t)QN * DN * 2);
  unsigned short* Qb    = (unsigned short*)alloc((size_t)QN * DN * 2);
  unsigned short* Gf_b  = (unsigned short*)alloc((size_t)QN * DN * 2);
  unsigned short* KVb   = (unsigned short*)alloc((size_t)SN * 512 * 2);
  unsigned short* attn_b = (unsigned short*)alloc((size_t)QN * DN * 2);
  float* x1             = (float*)alloc((size_t)QN * DN * 4);
  unsigned short* z_b   = (unsigned short*)alloc((size_t)QN * DN * 2);

  // L1: weight transpose + segment offsets + LN1  (input-only deps)
  fused_prep<<<2217, 256, 0, stream>>>(Wq, Wk, Wv, Wg, Wo, Wf1, Wf2,
                                       WqT, WkvT, WgT, WoT, Wf1T, Wf2T,
                                       q_idx, offs,
                                       query_tokens, ln1_g, ln1_b, qt_b);
  // L2: geo(stats->MLP->Gf) + KV gemm + Qf gemm
  fused_stage2<<<1152, 256, 0, stream>>>(query_pos, support_pos, offs, s_idx,
                                         Gw1, Gb1, Gw2, Gb2, WgT, Gf_b,
                                         support_feats, WkvT, KVb,
                                         qt_b, WqT, Qb);
  // L3: edge attention -> attn_b bf16  (software-pipelined gathers)
  attn_edge_kernel<<<QN / 4, 256, 0, stream>>>(Qb, Gf_b, KVb, s_idx, offs, log_tau, attn_b);
  // L4: x1 = attn @ Wo + bo + query_tokens, store fp32
  gemm64<false, true, false, true, true><<<dim3(QN / 64, DN / 64), 256, 0, stream>>>(
      attn_b, WoT, DN, 256, bo, query_tokens, x1, nullptr);
  // L5: LN2
  ln_kernel<<<QN / 4, 256, 0, stream>>>(x1, ln2_g, ln2_b, z_b);
  // L6: out = gelu(z@Wf1+bf1)@Wf2 + bf2 + x1  (fused FFN, h stays in LDS)
  ffn_kernel<<<QN / 16, 256, 0, stream>>>(z_b, Wf1T, bf1, Wf2T, bf2, x1, out);

  (void)in_sizes; (void)n_in; (void)out_size; (void)ws_size;
}

// Round 11
// 237.599 us; speedup vs baseline: 1.0890x; 1.0890x over previous
//
#include <hip/hip_runtime.h>
#include <math.h>

#define QN 8192
#define SN 32768
#define EN 131072
#define DN 256
#define HN 8
#define HDN 32
#define GEON 128
#define FFNN 512

typedef __attribute__((ext_vector_type(8))) short bf16x8;
typedef __attribute__((ext_vector_type(8))) unsigned short u16x8;
typedef __attribute__((ext_vector_type(4))) float f32x4;

__device__ __forceinline__ unsigned short f2b(float f) {
  union { float f; unsigned u; } v; v.f = f;
  unsigned u = v.u;
  u += 0x7fffu + ((u >> 16) & 1u);   // round-to-nearest-even
  return (unsigned short)(u >> 16);
}
__device__ __forceinline__ float b2f(unsigned short h) {
  union { unsigned u; float f; } v; v.u = ((unsigned)h) << 16; return v.f;
}
__device__ __forceinline__ float gelu_f(float x) {
  return 0.5f * x * (1.0f + erff(x * 0.70710678118654752440f));
}

// XOR swizzle in 8-element groups: phys_g = g ^ (row&7). Staging writes and
// fragment reads both land at the b128 minimum aliasing (conflict-free).
template <int KT>
__device__ __forceinline__ u16x8* lds_gk(unsigned short* base, int row, int col) {
  int g = (col >> 3) ^ (row & 7);
  return reinterpret_cast<u16x8*>(base + row * KT + g * 8);
}
// scalar u16 store into the same swizzled layout (KT=128)
__device__ __forceinline__ unsigned short* lds_gs128(unsigned short* base, int row, int col) {
  int g = (col >> 3) ^ (row & 7);
  return base + row * 128 + g * 8 + (col & 7);
}

// ================= L1: fused prep = transpose + seg_offsets + LN1 ==========
__global__ __launch_bounds__(256) void fused_prep(
    const float* Wq, const float* Wk, const float* Wv, const float* Wg,
    const float* Wo, const float* Wf1, const float* Wf2,
    unsigned short* WqT, unsigned short* WkvT, unsigned short* WgT,
    unsigned short* WoT, unsigned short* Wf1T, unsigned short* Wf2T,
    const int* q_idx, int* offs,
    const float* x_ln, const float* lng, const float* lnb, unsigned short* ln_out) {
  __shared__ float ts[64][65];
  int b = blockIdx.x;
  int t = threadIdx.x;
  if (b < 136) {
    const float* src; unsigned short* dst; int K, N, tile;
    if (b < 16)       { src = Wq;  dst = WqT;          K = 256; N = 256; tile = b; }
    else if (b < 32)  { src = Wk;  dst = WkvT;         K = 256; N = 256; tile = b - 16; }
    else if (b < 48)  { src = Wv;  dst = WkvT + 65536; K = 256; N = 256; tile = b - 32; }
    else if (b < 56)  { src = Wg;  dst = WgT;          K = 128; N = 256; tile = b - 48; }
    else if (b < 72)  { src = Wo;  dst = WoT;          K = 256; N = 256; tile = b - 56; }
    else if (b < 104) { src = Wf1; dst = Wf1T;         K = 256; N = 512; tile = b - 72; }
    else              { src = Wf2; dst = Wf2T;         K = 512; N = 256; tile = b - 104; }
    int ktiles = K >> 6;
    int k0 = (tile % ktiles) * 64, n0 = (tile / ktiles) * 64;
    int c4 = (t & 15) * 4;
    int r = t >> 4;
#pragma unroll
    for (int p = 0; p < 4; ++p) {
      int row = p * 16 + r;
      float4 v = *(const float4*)(src + (size_t)(k0 + row) * N + n0 + c4);
      ts[row][c4 + 0] = v.x; ts[row][c4 + 1] = v.y;
      ts[row][c4 + 2] = v.z; ts[row][c4 + 3] = v.w;
    }
    __syncthreads();
#pragma unroll
    for (int p = 0; p < 4; ++p) {
      int n = p * 16 + r;
      ushort4 o;
      o.x = f2b(ts[c4 + 0][n]); o.y = f2b(ts[c4 + 1][n]);
      o.z = f2b(ts[c4 + 2][n]); o.w = f2b(ts[c4 + 3][n]);
      *(ushort4*)(dst + (size_t)(n0 + n) * K + k0 + c4) = o;
    }
  } else if (b < 169) {
    int i = (b - 136) * 256 + t;
    if (i > QN) return;
    int lo = 0, hi = EN;
    while (lo < hi) {
      int mid = (lo + hi) >> 1;
      if (q_idx[mid] < i) lo = mid + 1; else hi = mid;
    }
    offs[i] = lo;
  } else {
    int row = (b - 169) * 4 + (t >> 6);
    int lane = t & 63;
    const float* xr = x_ln + (size_t)row * DN;
    float4 v = *(const float4*)(xr + lane * 4);
    float s = v.x + v.y + v.z + v.w;
    float ss = v.x * v.x + v.y * v.y + v.z * v.z + v.w * v.w;
#pragma unroll
    for (int msk = 1; msk <= 32; msk <<= 1) {
      s += __shfl_xor(s, msk);
      ss += __shfl_xor(ss, msk);
    }
    float mean = s * (1.f / 256.f);
    float var = ss * (1.f / 256.f) - mean * mean;
    float rs = 1.0f / sqrtf(var + 1e-5f);
    float4 gg = *(const float4*)(lng + lane * 4);
    float4 bb = *(const float4*)(lnb + lane * 4);
    unsigned short* o = ln_out + (size_t)row * DN + lane * 4;
    o[0] = f2b((v.x - mean) * rs * gg.x + bb.x);
    o[1] = f2b((v.y - mean) * rs * gg.y + bb.y);
    o[2] = f2b((v.z - mean) * rs * gg.z + bb.z);
    o[3] = f2b((v.w - mean) * rs * gg.w + bb.w);
  }
}

// ---------------- standalone LN (for LN2) ----------------
__global__ __launch_bounds__(256) void ln_kernel(
    const float* x, const float* g, const float* b, unsigned short* out) {
  int row = blockIdx.x * 4 + (threadIdx.x >> 6);
  int lane = threadIdx.x & 63;
  const float* xr = x + (size_t)row * DN;
  float4 v = *(const float4*)(xr + lane * 4);
  float s = v.x + v.y + v.z + v.w;
  float ss = v.x * v.x + v.y * v.y + v.z * v.z + v.w * v.w;
#pragma unroll
  for (int msk = 1; msk <= 32; msk <<= 1) {
    s += __shfl_xor(s, msk);
    ss += __shfl_xor(ss, msk);
  }
  float mean = s * (1.f / 256.f);
  float var = ss * (1.f / 256.f) - mean * mean;
  float rs = 1.0f / sqrtf(var + 1e-5f);
  float4 gg = *(const float4*)(g + lane * 4);
  float4 bb = *(const float4*)(b + lane * 4);
  unsigned short* o = out + (size_t)row * DN + lane * 4;
  o[0] = f2b((v.x - mean) * rs * gg.x + bb.x);
  o[1] = f2b((v.y - mean) * rs * gg.y + bb.y);
  o[2] = f2b((v.z - mean) * rs * gg.z + bb.z);
  o[3] = f2b((v.w - mean) * rs * gg.w + bb.w);
}

// ================= device bodies for fused stage 2 =========================

// ---- KV GEMM body (R9-proven: dense-coalesced A stage, B reg-prefetch) ----
__device__ __forceinline__ void kv_body(
    char* smem, const float* A, const unsigned short* BT, unsigned short* KVb,
    int bm, int t) {
  unsigned short* As = (unsigned short*)smem;            // 32 KB
  unsigned short* Bs = (unsigned short*)(smem + 32768);  // 16 KB
  int w = t >> 6, lane = t & 63;
  int quad = lane >> 4, l16 = lane & 15;
  int wr = w >> 1, wc = w & 1;
  {
    int prow = t >> 6;
    int c4 = (t & 63) * 4;
#pragma unroll
    for (int p = 0; p < 16; ++p) {
      int lr = p * 4 + prow;
      float4 f = *(const float4*)(A + (size_t)(bm + lr) * 256 + c4);
      ushort4 u;
      u.x = f2b(f.x); u.y = f2b(f.y); u.z = f2b(f.z); u.w = f2b(f.w);
      int g = (c4 >> 3) ^ (lr & 7);
      *(ushort4*)(As + lr * 256 + g * 8 + (c4 & 7)) = u;
    }
  }
  int brow = t >> 3, bsub = t & 7;
  u16x8 pre[4];
  {
    const unsigned short* Bg = BT + (size_t)brow * 256 + bsub * 32;
#pragma unroll
    for (int i = 0; i < 4; ++i) pre[i] = *reinterpret_cast<const u16x8*>(Bg + i * 8);
  }
  for (int ct = 0; ct < 16; ++ct) {
#pragma unroll
    for (int i = 0; i < 4; ++i)
      *lds_gk<256>(Bs, brow, bsub * 32 + i * 8) = pre[i];
    __syncthreads();
    if (ct < 15) {
      const unsigned short* Bg = BT + (size_t)((ct + 1) * 32 + brow) * 256 + bsub * 32;
#pragma unroll
      for (int i = 0; i < 4; ++i) pre[i] = *reinterpret_cast<const u16x8*>(Bg + i * 8);
    }
    f32x4 acc[2];
    acc[0] = (f32x4){0.f, 0.f, 0.f, 0.f};
    acc[1] = (f32x4){0.f, 0.f, 0.f, 0.f};
#pragma unroll
    for (int k = 0; k < 8; ++k) {
      bf16x8 a0 = *reinterpret_cast<bf16x8*>(lds_gk<256>(As, wr * 32 + l16, k * 32 + quad * 8));
      bf16x8 a1 = *reinterpret_cast<bf16x8*>(lds_gk<256>(As, wr * 32 + 16 + l16, k * 32 + quad * 8));
      bf16x8 b0 = *reinterpret_cast<bf16x8*>(lds_gk<256>(Bs, wc * 16 + l16, k * 32 + quad * 8));
      acc[0] = __builtin_amdgcn_mfma_f32_16x16x32_bf16(a0, b0, acc[0], 0, 0, 0);
      acc[1] = __builtin_amdgcn_mfma_f32_16x16x32_bf16(a1, b0, acc[1], 0, 0, 0);
    }
#pragma unroll
    for (int i = 0; i < 2; ++i)
#pragma unroll
      for (int r = 0; r < 4; ++r) {
        int rw = bm + wr * 32 + i * 16 + quad * 4 + r;
        int col = ct * 32 + wc * 16 + l16;
        KVb[(size_t)rw * 512 + col] = f2b(acc[i][r]);
      }
    __syncthreads();
  }
}

// ---- gemm64 body: 64x64 tile, 10.2KB LDS, k-step register prefetch --------
template <bool A_FP32, bool HAS_BIAS, bool DO_GELU, bool HAS_RESID, bool STORE_F32>
__device__ __forceinline__ void gemm64_body(
    char* smem, const void* Ap, const unsigned short* BT, int N, int K,
    const float* bias, const float* resid, float* outF, unsigned short* outB,
    int bm, int bn, int t) {
  unsigned short (*As)[40] = (unsigned short(*)[40])smem;
  unsigned short (*Bs)[40] = (unsigned short(*)[40])(smem + 5120);
  int w = t >> 6, lane = t & 63;
  int wr = w >> 1, wc = w & 1;
  int quad = lane >> 4, l16 = lane & 15;
  int row = t >> 2, chunk = t & 3;

  const float* AgF = (const float*)Ap + (size_t)(bm + row) * K + chunk * 8;
  const unsigned short* AgB = (const unsigned short*)Ap + (size_t)(bm + row) * K + chunk * 8;
  const unsigned short* Bg = BT + (size_t)(bn + row) * K + chunk * 8;

  float4 pf0, pf1;
  u16x8 pa, pb;
  if (A_FP32) { pf0 = *(const float4*)AgF; pf1 = *(const float4*)(AgF + 4); }
  else        { pa = *(const u16x8*)AgB; }
  pb = *(const u16x8*)Bg;

  f32x4 acc[2][2];
#pragma unroll
  for (int i = 0; i < 2; ++i)
#pragma unroll
    for (int j = 0; j < 2; ++j) acc[i][j] = (f32x4){0.f, 0.f, 0.f, 0.f};

  for (int k0 = 0; k0 < K; k0 += 32) {
    u16x8 ua;
    if (A_FP32) {
      ua[0] = f2b(pf0.x); ua[1] = f2b(pf0.y); ua[2] = f2b(pf0.z); ua[3] = f2b(pf0.w);
      ua[4] = f2b(pf1.x); ua[5] = f2b(pf1.y); ua[6] = f2b(pf1.z); ua[7] = f2b(pf1.w);
    } else {
      ua = pa;
    }
    *reinterpret_cast<u16x8*>(&As[row][chunk * 8]) = ua;
    *reinterpret_cast<u16x8*>(&Bs[row][chunk * 8]) = pb;
    __syncthreads();
    if (k0 + 32 < K) {
      if (A_FP32) { pf0 = *(const float4*)(AgF + k0 + 32); pf1 = *(const float4*)(AgF + k0 + 36); }
      else        { pa = *(const u16x8*)(AgB + k0 + 32); }
      pb = *(const u16x8*)(Bg + k0 + 32);
    }
    bf16x8 a0 = *reinterpret_cast<const bf16x8*>(&As[wr * 32 + l16][quad * 8]);
    bf16x8 a1 = *reinterpret_cast<const bf16x8*>(&As[wr * 32 + 16 + l16][quad * 8]);
    bf16x8 b0 = *reinterpret_cast<const bf16x8*>(&Bs[wc * 32 + l16][quad * 8]);
    bf16x8 b1 = *reinterpret_cast<const bf16x8*>(&Bs[wc * 32 + 16 + l16][quad * 8]);
    acc[0][0] = __builtin_amdgcn_mfma_f32_16x16x32_bf16(a0, b0, acc[0][0], 0, 0, 0);
    acc[0][1] = __builtin_amdgcn_mfma_f32_16x16x32_bf16(a0, b1, acc[0][1], 0, 0, 0);
    acc[1][0] = __builtin_amdgcn_mfma_f32_16x16x32_bf16(a1, b0, acc[1][0], 0, 0, 0);
    acc[1][1] = __builtin_amdgcn_mfma_f32_16x16x32_bf16(a1, b1, acc[1][1], 0, 0, 0);
    __syncthreads();
  }

#pragma unroll
  for (int i = 0; i < 2; ++i)
#pragma unroll
    for (int j = 0; j < 2; ++j) {
      int col = bn + wc * 32 + j * 16 + l16;
      float bv = HAS_BIAS ? bias[col] : 0.f;
#pragma unroll
      for (int r = 0; r < 4; ++r) {
        int rw = bm + wr * 32 + i * 16 + quad * 4 + r;
        float v = acc[i][j][r] + bv;
        if (DO_GELU) v = gelu_f(v);
        if (HAS_RESID) v += resid[(size_t)rw * N + col];
        if (STORE_F32) outF[(size_t)rw * N + col] = v;
        else outB[(size_t)rw * N + col] = f2b(v);
      }
    }
}

// ---- geo mega body: stats -> MLP(2-pass acc[16], R6-verified) -> Gf GEMM --
// smem: [0,3072) rs f32[64][12]; [3072,19456) geoL bf16 swizzled [64][128];
// [19456,35840) h1 f32[32][128] (per half) / Bs bf16[64][128] in phase 3.
// acc[16] halves the MLP register footprint vs acc[32]: the kernel-wide VGPR
// allocation (max over branches) drops below the 170 = 3-waves/SIMD boundary,
// raising resident blocks/CU from 2 to 3 for ALL of fused_stage2.
__device__ __forceinline__ void geo_body(
    char* smem, const float* qpos, const float* spos, const int* offs,
    const int* s_idx, const float* Gw1, const float* Gb1,
    const float* Gw2, const float* Gb2, const unsigned short* WgT,
    unsigned short* Gf_b, int qb, int t) {
  float (*rs)[12] = (float(*)[12])smem;
  unsigned short* geoL = (unsigned short*)(smem + 3072);
  float* h1 = (float*)(smem + 19456);                 // [32][128] per half
  unsigned short* Bs = (unsigned short*)(smem + 19456);

  // ---- phase 1: stats (4 lanes per query) ----
  {
    int q = qb + (t >> 2);
    int sub = t & 3;
    int e0 = offs[q], e1 = offs[q + 1];
    float qx = qpos[q * 3 + 0], qy = qpos[q * 3 + 1], qz = qpos[q * 3 + 2];
    float cnt = 0.f, sx = 0.f, sy = 0.f, sz = 0.f, sxx = 0.f, syy = 0.f, szz = 0.f;
    float mnx = 1e30f, mny = 1e30f, mnz = 1e30f, mxx = -1e30f, mxy = -1e30f, mxz = -1e30f;
    for (int e = e0 + sub; e < e1; e += 4) {
      int s = s_idx[e];
      float rx = spos[s * 3 + 0] - qx;
      float ry = spos[s * 3 + 1] - qy;
      float rz = spos[s * 3 + 2] - qz;
      cnt += 1.f;
      sx += rx; sy += ry; sz += rz;
      sxx += rx * rx; syy += ry * ry; szz += rz * rz;
      mnx = fminf(mnx, rx); mny = fminf(mny, ry); mnz = fminf(mnz, rz);
      mxx = fmaxf(mxx, rx); mxy = fmaxf(mxy, ry); mxz = fmaxf(mxz, rz);
    }
#pragma unroll
    for (int msk = 1; msk <= 2; msk <<= 1) {
      cnt += __shfl_xor(cnt, msk);
      sx += __shfl_xor(sx, msk); sy += __shfl_xor(sy, msk); sz += __shfl_xor(sz, msk);
      sxx += __shfl_xor(sxx, msk); syy += __shfl_xor(syy, msk); szz += __shfl_xor(szz, msk);
      mnx = fminf(mnx, __shfl_xor(mnx, msk));
      mny = fminf(mny, __shfl_xor(mny, msk));
      mnz = fminf(mnz, __shfl_xor(mnz, msk));
      mxx = fmaxf(mxx, __shfl_xor(mxx, msk));
      mxy = fmaxf(mxy, __shfl_xor(mxy, msk));
      mxz = fmaxf(mxz, __shfl_xor(mxz, msk));
    }
    if (sub == 0) {
      int qq = t >> 2;
      float c = fmaxf(cnt, 1.f);
      float mx_ = sx / c, my_ = sy / c, mz_ = sz / c;
      float vx = fmaxf(sxx / c - mx_ * mx_, 0.f);
      float vy = fmaxf(syy / c - my_ * my_, 0.f);
      float vz = fmaxf(szz / c - mz_ * mz_, 0.f);
      rs[qq][0] = mx_; rs[qq][1] = my_; rs[qq][2] = mz_;
      rs[qq][3] = sqrtf(vx); rs[qq][4] = sqrtf(vy); rs[qq][5] = sqrtf(vz);
      rs[qq][6] = fminf(fmaxf(mnx, -100.f), 100.f);
      rs[qq][7] = fminf(fmaxf(mny, -100.f), 100.f);
      rs[qq][8] = fminf(fmaxf(mnz, -100.f), 100.f);
      rs[qq][9] = fminf(fmaxf(mxx, -100.f), 100.f);
      rs[qq][10] = fminf(fmaxf(mxy, -100.f), 100.f);
      rs[qq][11] = fminf(fmaxf(mxz, -100.f), 100.f);
    }
  }
  __syncthreads();

  // ---- phase 2: MLP, two passes of 32 queries (h1 f32 [32][128]) ----
  {
    int j = t & 127;
    int grp = t >> 7;                 // 0..1
    for (int half = 0; half < 2; ++half) {
      int qloc = grp * 16;
      int qglob = half * 32 + qloc;
      float acc[16];
      float b1 = Gb1[j];
#pragma unroll
      for (int qq = 0; qq < 16; ++qq) acc[qq] = b1;
      for (int i = 0; i < 12; ++i) {
        float wv = Gw1[i * GEON + j];
#pragma unroll
        for (int qq = 0; qq < 16; ++qq) acc[qq] += rs[qglob + qq][i] * wv;
      }
#pragma unroll
      for (int qq = 0; qq < 16; ++qq) h1[(qloc + qq) * 128 + j] = gelu_f(acc[qq]);
      __syncthreads();
      float acc2[16];
      float b2 = Gb2[j];
#pragma unroll
      for (int qq = 0; qq < 16; ++qq) acc2[qq] = b2;
      for (int k = 0; k < 128; ++k) {
        float wv = Gw2[k * GEON + j];
#pragma unroll
        for (int qq = 0; qq < 16; ++qq) acc2[qq] += h1[(qloc + qq) * 128 + k] * wv;
      }
#pragma unroll
      for (int qq = 0; qq < 16; ++qq)
        *lds_gs128(geoL, qglob + qq, j) = f2b(gelu_f(acc2[qq]));
      __syncthreads();   // h1 reusable next pass / final: geoL visible, h1 dead
    }
  }

  // ---- phase 3: Gf[qb..qb+63, 0..255] = geo @ Wg via MFMA ----
  {
    int w = t >> 6, lane = t & 63;
    int wr = w >> 1, wc = w & 1;
    int quad = lane >> 4, l16 = lane & 15;
    int row = t >> 2, sub = t & 3;
    for (int ct = 0; ct < 4; ++ct) {
      int bn = ct * 64;
      {
        const unsigned short* Bg = WgT + (size_t)(bn + row) * 128 + sub * 32;
#pragma unroll
        for (int i = 0; i < 4; ++i)
          *lds_gk<128>(Bs, row, sub * 32 + i * 8) = *reinterpret_cast<const u16x8*>(Bg + i * 8);
      }
      __syncthreads();
      f32x4 acc[2][2];
#pragma unroll
      for (int i = 0; i < 2; ++i)
#pragma unroll
        for (int j = 0; j < 2; ++j) acc[i][j] = (f32x4){0.f, 0.f, 0.f, 0.f};
#pragma unroll
      for (int k = 0; k < 4; ++k) {
        bf16x8 a0 = *reinterpret_cast<bf16x8*>(lds_gk<128>(geoL, wr * 32 + l16, k * 32 + quad * 8));
        bf16x8 a1 = *reinterpret_cast<bf16x8*>(lds_gk<128>(geoL, wr * 32 + 16 + l16, k * 32 + quad * 8));
        bf16x8 b0 = *reinterpret_cast<bf16x8*>(lds_gk<128>(Bs, wc * 32 + l16, k * 32 + quad * 8));
        bf16x8 b1 = *reinterpret_cast<bf16x8*>(lds_gk<128>(Bs, wc * 32 + 16 + l16, k * 32 + quad * 8));
        acc[0][0] = __builtin_amdgcn_mfma_f32_16x16x32_bf16(a0, b0, acc[0][0], 0, 0, 0);
        acc[0][1] = __builtin_amdgcn_mfma_f32_16x16x32_bf16(a0, b1, acc[0][1], 0, 0, 0);
        acc[1][0] = __builtin_amdgcn_mfma_f32_16x16x32_bf16(a1, b0, acc[1][0], 0, 0, 0);
        acc[1][1] = __builtin_amdgcn_mfma_f32_16x16x32_bf16(a1, b1, acc[1][1], 0, 0, 0);
      }
#pragma unroll
      for (int i = 0; i < 2; ++i)
#pragma unroll
        for (int j = 0; j < 2; ++j) {
          int col = bn + wc * 32 + j * 16 + l16;
#pragma unroll
          for (int r = 0; r < 4; ++r) {
            int rw = qb + wr * 32 + i * 16 + quad * 4 + r;
            Gf_b[(size_t)rw * 256 + col] = f2b(acc[i][j][r]);
          }
        }
      __syncthreads();
    }
  }
}

// ================= L2: fused stage 2 = geo-mega + kv + Qf ==================
// smem union = kv's 48KB. geo acc[16] keeps kernel VGPR under the 170
// (3 waves/SIMD) boundary -> 3 blocks/CU resident (was 2 at VGPR=200).
__global__ __launch_bounds__(256) void fused_stage2(
    const float* qpos, const float* spos, const int* offs, const int* s_idx,
    const float* Gw1, const float* Gb1, const float* Gw2, const float* Gb2,
    const unsigned short* WgT, unsigned short* Gf_b,
    const float* support_feats, const unsigned short* WkvT, unsigned short* KVb,
    const unsigned short* qt_b, const unsigned short* WqT, unsigned short* Qb) {
  __shared__ __align__(16) char smem[49152];
  int b = blockIdx.x;
  int t = threadIdx.x;
  if (b < 128) {
    geo_body(smem, qpos, spos, offs, s_idx, Gw1, Gb1, Gw2, Gb2, WgT, Gf_b, b * 64, t);
  } else if (b < 640) {
    kv_body(smem, support_feats, WkvT, KVb, (b - 128) * 64, t);
  } else {
    int bb = b - 640;
    int bm = (bb & 127) * 64, bn = (bb >> 7) * 64;
    gemm64_body<false, false, false, false, false>(
        smem, qt_b, WqT, DN, 256, nullptr, nullptr, nullptr, Qb, bm, bn, t);
  }
}

// ---------------- standalone gemm64 wrapper (Wo, FFN1, FFN2) ---------------
template <bool A_FP32, bool HAS_BIAS, bool DO_GELU, bool HAS_RESID, bool STORE_F32>
__global__ __launch_bounds__(256) void gemm64(
    const void* Ap, const unsigned short* BT, int N, int K,
    const float* bias, const float* resid, float* outF, unsigned short* outB) {
  __shared__ __align__(16) char smem[10240];
  gemm64_body<A_FP32, HAS_BIAS, DO_GELU, HAS_RESID, STORE_F32>(
      smem, Ap, BT, N, K, bias, resid, outF, outB,
      blockIdx.x * 64, blockIdx.y * 64, threadIdx.x);
}

// ---------------- edge attention: one wave/query, 4 edges per iteration ----
// (R9-proven version: compiler-scheduled gathers, no manual pipeline.)
__global__ __launch_bounds__(256) void attn_edge_kernel(
    const unsigned short* Qb, const unsigned short* Gfb, const unsigned short* KVb,
    const int* s_idx, const int* offs, const float* log_tau, unsigned short* attn_b) {
  int q = blockIdx.x * 4 + (threadIdx.x >> 6);
  int lane = threadIdx.x & 63;
  int slot = lane >> 4;
  int sl = lane & 15;
  int d0 = sl * 16;
  int e0 = offs[q], e1 = offs[q + 1];
  float invs = expf(-log_tau[0]) * 0.17677669529663687f;  // 1/(sqrt(32)*tau)
  u16x8 qu0 = *(const u16x8*)(Qb + (size_t)q * DN + d0);
  u16x8 qu1 = *(const u16x8*)(Qb + (size_t)q * DN + d0 + 8);
  u16x8 gu0 = *(const u16x8*)(Gfb + (size_t)q * DN + d0);
  u16x8 gu1 = *(const u16x8*)(Gfb + (size_t)q * DN + d0 + 8);
  float qf[16], gf[16];
#pragma unroll
  for (int j = 0; j < 8; ++j) {
    qf[j] = b2f(qu0[j]) * invs; qf[j + 8] = b2f(qu1[j]) * invs;
    gf[j] = b2f(gu0[j]);        gf[j + 8] = b2f(gu1[j]);
  }
  const float NEG = -1e30f;
  float m = -INFINITY, l = 0.f;
  float a[16];
#pragma unroll
  for (int j = 0; j < 16; ++j) a[j] = 0.f;
  for (int e = e0; e < e1; e += 4) {
    int ee = e + slot;
    bool valid = ee < e1;
    int s = s_idx[valid ? ee : (e1 - 1)];
    const unsigned short* kr = KVb + (size_t)s * 512 + d0;
    u16x8 ku0 = *(const u16x8*)kr;
    u16x8 ku1 = *(const u16x8*)(kr + 8);
    u16x8 vu0 = *(const u16x8*)(kr + 256);
    u16x8 vu1 = *(const u16x8*)(kr + 264);
    float p = 0.f;
#pragma unroll
    for (int j = 0; j < 8; ++j) {
      p += qf[j] * b2f(ku0[j]);
      p += qf[j + 8] * b2f(ku1[j]);
    }
    p += __shfl_xor(p, 1);
    if (!valid) p = -INFINITY;
    float mnew = fmaxf(m, p);
    float sc = (m > NEG) ? __expf(m - mnew) : 0.f;
    float we = valid ? __expf(p - mnew) : 0.f;
    l = l * sc + we;
#pragma unroll
    for (int j = 0; j < 8; ++j) {
      a[j] = a[j] * sc + we * b2f(vu0[j]);
      a[j + 8] = a[j + 8] * sc + we * b2f(vu1[j]);
    }
    m = mnew;
  }
#pragma unroll
  for (int msk = 16; msk <= 32; msk <<= 1) {
    float om = __shfl_xor(m, msk);
    float ol = __shfl_xor(l, msk);
    float M2 = fmaxf(m, om);
    float ws = (m > NEG) ? __expf(m - M2) : 0.f;
    float wo = (om > NEG) ? __expf(om - M2) : 0.f;
    l = l * ws + ol * wo;
#pragma unroll
    for (int j = 0; j < 16; ++j) {
      float oa = __shfl_xor(a[j], msk);
      a[j] = a[j] * ws + oa * wo;
    }
    m = M2;
  }
  float M = fmaxf(m, 0.f);
  float em = (m > NEG) ? __expf(m - M) : 0.f;
  float denom = fmaxf(l * em, 1e-8f);
  float f = em / denom;
  float sa = l * f;              // = sum(alpha)
  if (slot == 0) {
    u16x8 o0, o1;
#pragma unroll
    for (int j = 0; j < 8; ++j) {
      o0[j] = f2b(a[j] * f + gf[j] * sa);
      o1[j] = f2b(a[j + 8] * f + gf[j + 8] * sa);
    }
    *(u16x8*)(attn_b + (size_t)q * DN + d0) = o0;
    *(u16x8*)(attn_b + (size_t)q * DN + d0 + 8) = o1;
  }
}

extern "C" void kernel_launch(void* const* d_in, const int* in_sizes, int n_in,
                              void* d_out, int out_size, void* d_ws, size_t ws_size,
                              hipStream_t stream) {
  const float* query_tokens  = (const float*)d_in[0];
  const float* query_pos     = (const float*)d_in[1];
  const float* support_feats = (const float*)d_in[2];
  const float* support_pos   = (const float*)d_in[3];
  const float* Wq  = (const float*)d_in[4];
  const float* Wk  = (const float*)d_in[5];
  const float* Wv  = (const float*)d_in[6];
  const float* Wg  = (const float*)d_in[7];
  const float* Wo  = (const float*)d_in[8];
  const float* bo  = (const float*)d_in[9];
  const float* log_tau = (const float*)d_in[10];
  const float* ln1_g = (const float*)d_in[11];
  const float* ln1_b = (const float*)d_in[12];
  const float* ln2_g = (const float*)d_in[13];
  const float* ln2_b = (const float*)d_in[14];
  const float* Wf1 = (const float*)d_in[15];
  const float* bf1 = (const float*)d_in[16];
  const float* Wf2 = (const float*)d_in[17];
  const float* bf2 = (const float*)d_in[18];
  const float* Gw1 = (const float*)d_in[19];
  const float* Gb1 = (const float*)d_in[20];
  const float* Gw2 = (const float*)d_in[21];
  const float* Gb2 = (const float*)d_in[22];
  const int* q_idx = (const int*)d_in[23];
  const int* s_idx = (const int*)d_in[24];
  float* out = (float*)d_out;

  char* ws = (char*)d_ws;
  size_t off = 0;
  auto alloc = [&](size_t bytes) -> void* {
    void* p = ws + off;
    off = (off + bytes + 255) & ~(size_t)255;
    return p;
  };
  unsigned short* WqT  = (unsigned short*)alloc(65536 * 2);
  unsigned short* WkvT = (unsigned short*)alloc(131072 * 2);
  unsigned short* WgT  = (unsigned short*)alloc(32768 * 2);
  unsigned short* WoT  = (unsigned short*)alloc(65536 * 2);
  unsigned short* Wf1T = (unsigned short*)alloc(131072 * 2);
  unsigned short* Wf2T = (unsigned short*)alloc(131072 * 2);
  int* offs            = (int*)alloc((QN + 1) * 4);
  unsigned short* qt_b  = (unsigned short*)alloc((size_t)QN * DN * 2);
  unsigned short* Qb    = (unsigned short*)alloc((size_t)QN * DN * 2);
  unsigned short* Gf_b  = (unsigned short*)alloc((size_t)QN * DN * 2);
  unsigned short* KVb   = (unsigned short*)alloc((size_t)SN * 512 * 2);
  unsigned short* attn_b = (unsigned short*)alloc((size_t)QN * DN * 2);
  float* x1             = (float*)alloc((size_t)QN * DN * 4);
  unsigned short* z_b   = (unsigned short*)alloc((size_t)QN * DN * 2);
  unsigned short* h_b   = (unsigned short*)alloc((size_t)QN * FFNN * 2);

  // L1: weight transpose + segment offsets + LN1  (input-only deps)
  fused_prep<<<2217, 256, 0, stream>>>(Wq, Wk, Wv, Wg, Wo, Wf1, Wf2,
                                       WqT, WkvT, WgT, WoT, Wf1T, Wf2T,
                                       q_idx, offs,
                                       query_tokens, ln1_g, ln1_b, qt_b);
  // L2: geo(stats->MLP->Gf) + KV gemm + Qf gemm  (co-scheduled)
  fused_stage2<<<1152, 256, 0, stream>>>(query_pos, support_pos, offs, s_idx,
                                         Gw1, Gb1, Gw2, Gb2, WgT, Gf_b,
                                         support_feats, WkvT, KVb,
                                         qt_b, WqT, Qb);
  // L3: edge attention -> attn_b bf16
  attn_edge_kernel<<<QN / 4, 256, 0, stream>>>(Qb, Gf_b, KVb, s_idx, offs, log_tau, attn_b);
  // L4: x1 = attn @ Wo + bo + query_tokens, store fp32
  gemm64<false, true, false, true, true><<<dim3(QN / 64, DN / 64), 256, 0, stream>>>(
      attn_b, WoT, DN, 256, bo, query_tokens, x1, nullptr);
  // L5: LN2
  ln_kernel<<<QN / 4, 256, 0, stream>>>(x1, ln2_g, ln2_b, z_b);
  // L6: h = gelu(z @ Wf1 + bf1), store bf16
  gemm64<false, true, true, false, false><<<dim3(QN / 64, FFNN / 64), 256, 0, stream>>>(
      z_b, Wf1T, FFNN, 256, bf1, nullptr, nullptr, h_b);
  // L7: out = h @ Wf2 + bf2 + x1, store fp32 -> d_out
  gemm64<false, true, false, true, true><<<dim3(QN / 64, DN / 64), 256, 0, stream>>>(
      h_b, Wf2T, DN, 512, bf2, x1, out, nullptr);

  (void)in_sizes; (void)n_in; (void)out_size; (void)ws_size;
}

// Round 12
// 237.369 us; speedup vs baseline: 1.0900x; 1.0010x over previous
//
#include <hip/hip_runtime.h>
#include <math.h>

#define QN 8192
#define SN 32768
#define EN 131072
#define DN 256
#define HN 8
#define HDN 32
#define GEON 128
#define FFNN 512

typedef __attribute__((ext_vector_type(8))) short bf16x8;
typedef __attribute__((ext_vector_type(8))) unsigned short u16x8;
typedef __attribute__((ext_vector_type(4))) float f32x4;

__device__ __forceinline__ unsigned short f2b(float f) {
  union { float f; unsigned u; } v; v.f = f;
  unsigned u = v.u;
  u += 0x7fffu + ((u >> 16) & 1u);   // round-to-nearest-even
  return (unsigned short)(u >> 16);
}
__device__ __forceinline__ float b2f(unsigned short h) {
  union { unsigned u; float f; } v; v.u = ((unsigned)h) << 16; return v.f;
}
__device__ __forceinline__ float gelu_f(float x) {
  return 0.5f * x * (1.0f + erff(x * 0.70710678118654752440f));
}

// XOR swizzle in 8-element groups: phys_g = g ^ (row&7). Staging writes and
// fragment reads both land at the b128 minimum aliasing (conflict-free).
template <int KT>
__device__ __forceinline__ u16x8* lds_gk(unsigned short* base, int row, int col) {
  int g = (col >> 3) ^ (row & 7);
  return reinterpret_cast<u16x8*>(base + row * KT + g * 8);
}
// scalar u16 store into the same swizzled layout (KT=128)
__device__ __forceinline__ unsigned short* lds_gs128(unsigned short* base, int row, int col) {
  int g = (col >> 3) ^ (row & 7);
  return base + row * 128 + g * 8 + (col & 7);
}

// ================= L1: fused prep = transpose + seg_offsets + LN1 ==========
__global__ __launch_bounds__(256) void fused_prep(
    const float* Wq, const float* Wk, const float* Wv, const float* Wg,
    const float* Wo, const float* Wf1, const float* Wf2,
    unsigned short* WqT, unsigned short* WkvT, unsigned short* WgT,
    unsigned short* WoT, unsigned short* Wf1T, unsigned short* Wf2T,
    const int* q_idx, int* offs,
    const float* x_ln, const float* lng, const float* lnb, unsigned short* ln_out) {
  __shared__ float ts[64][65];
  int b = blockIdx.x;
  int t = threadIdx.x;
  if (b < 136) {
    const float* src; unsigned short* dst; int K, N, tile;
    if (b < 16)       { src = Wq;  dst = WqT;          K = 256; N = 256; tile = b; }
    else if (b < 32)  { src = Wk;  dst = WkvT;         K = 256; N = 256; tile = b - 16; }
    else if (b < 48)  { src = Wv;  dst = WkvT + 65536; K = 256; N = 256; tile = b - 32; }
    else if (b < 56)  { src = Wg;  dst = WgT;          K = 128; N = 256; tile = b - 48; }
    else if (b < 72)  { src = Wo;  dst = WoT;          K = 256; N = 256; tile = b - 56; }
    else if (b < 104) { src = Wf1; dst = Wf1T;         K = 256; N = 512; tile = b - 72; }
    else              { src = Wf2; dst = Wf2T;         K = 512; N = 256; tile = b - 104; }
    int ktiles = K >> 6;
    int k0 = (tile % ktiles) * 64, n0 = (tile / ktiles) * 64;
    int c4 = (t & 15) * 4;
    int r = t >> 4;
#pragma unroll
    for (int p = 0; p < 4; ++p) {
      int row = p * 16 + r;
      float4 v = *(const float4*)(src + (size_t)(k0 + row) * N + n0 + c4);
      ts[row][c4 + 0] = v.x; ts[row][c4 + 1] = v.y;
      ts[row][c4 + 2] = v.z; ts[row][c4 + 3] = v.w;
    }
    __syncthreads();
#pragma unroll
    for (int p = 0; p < 4; ++p) {
      int n = p * 16 + r;
      ushort4 o;
      o.x = f2b(ts[c4 + 0][n]); o.y = f2b(ts[c4 + 1][n]);
      o.z = f2b(ts[c4 + 2][n]); o.w = f2b(ts[c4 + 3][n]);
      *(ushort4*)(dst + (size_t)(n0 + n) * K + k0 + c4) = o;
    }
  } else if (b < 169) {
    int i = (b - 136) * 256 + t;
    if (i > QN) return;
    int lo = 0, hi = EN;
    while (lo < hi) {
      int mid = (lo + hi) >> 1;
      if (q_idx[mid] < i) lo = mid + 1; else hi = mid;
    }
    offs[i] = lo;
  } else {
    int row = (b - 169) * 4 + (t >> 6);
    int lane = t & 63;
    const float* xr = x_ln + (size_t)row * DN;
    float4 v = *(const float4*)(xr + lane * 4);
    float s = v.x + v.y + v.z + v.w;
    float ss = v.x * v.x + v.y * v.y + v.z * v.z + v.w * v.w;
#pragma unroll
    for (int msk = 1; msk <= 32; msk <<= 1) {
      s += __shfl_xor(s, msk);
      ss += __shfl_xor(ss, msk);
    }
    float mean = s * (1.f / 256.f);
    float var = ss * (1.f / 256.f) - mean * mean;
    float rs = 1.0f / sqrtf(var + 1e-5f);
    float4 gg = *(const float4*)(lng + lane * 4);
    float4 bb = *(const float4*)(lnb + lane * 4);
    unsigned short* o = ln_out + (size_t)row * DN + lane * 4;
    o[0] = f2b((v.x - mean) * rs * gg.x + bb.x);
    o[1] = f2b((v.y - mean) * rs * gg.y + bb.y);
    o[2] = f2b((v.z - mean) * rs * gg.z + bb.z);
    o[3] = f2b((v.w - mean) * rs * gg.w + bb.w);
  }
}

// ---------------- standalone LN (for LN2) ----------------
__global__ __launch_bounds__(256) void ln_kernel(
    const float* x, const float* g, const float* b, unsigned short* out) {
  int row = blockIdx.x * 4 + (threadIdx.x >> 6);
  int lane = threadIdx.x & 63;
  const float* xr = x + (size_t)row * DN;
  float4 v = *(const float4*)(xr + lane * 4);
  float s = v.x + v.y + v.z + v.w;
  float ss = v.x * v.x + v.y * v.y + v.z * v.z + v.w * v.w;
#pragma unroll
  for (int msk = 1; msk <= 32; msk <<= 1) {
    s += __shfl_xor(s, msk);
    ss += __shfl_xor(ss, msk);
  }
  float mean = s * (1.f / 256.f);
  float var = ss * (1.f / 256.f) - mean * mean;
  float rs = 1.0f / sqrtf(var + 1e-5f);
  float4 gg = *(const float4*)(g + lane * 4);
  float4 bb = *(const float4*)(b + lane * 4);
  unsigned short* o = out + (size_t)row * DN + lane * 4;
  o[0] = f2b((v.x - mean) * rs * gg.x + bb.x);
  o[1] = f2b((v.y - mean) * rs * gg.y + bb.y);
  o[2] = f2b((v.z - mean) * rs * gg.z + bb.z);
  o[3] = f2b((v.w - mean) * rs * gg.w + bb.w);
}

// ================= device bodies for fused stage 2 =========================

// ---- KV GEMM body (R9-proven: dense-coalesced A stage, B reg-prefetch) ----
__device__ __forceinline__ void kv_body(
    char* smem, const float* A, const unsigned short* BT, unsigned short* KVb,
    int bm, int t) {
  unsigned short* As = (unsigned short*)smem;            // 32 KB
  unsigned short* Bs = (unsigned short*)(smem + 32768);  // 16 KB
  int w = t >> 6, lane = t & 63;
  int quad = lane >> 4, l16 = lane & 15;
  int wr = w >> 1, wc = w & 1;
  {
    int prow = t >> 6;
    int c4 = (t & 63) * 4;
#pragma unroll
    for (int p = 0; p < 16; ++p) {
      int lr = p * 4 + prow;
      float4 f = *(const float4*)(A + (size_t)(bm + lr) * 256 + c4);
      ushort4 u;
      u.x = f2b(f.x); u.y = f2b(f.y); u.z = f2b(f.z); u.w = f2b(f.w);
      int g = (c4 >> 3) ^ (lr & 7);
      *(ushort4*)(As + lr * 256 + g * 8 + (c4 & 7)) = u;
    }
  }
  int brow = t >> 3, bsub = t & 7;
  u16x8 pre[4];
  {
    const unsigned short* Bg = BT + (size_t)brow * 256 + bsub * 32;
#pragma unroll
    for (int i = 0; i < 4; ++i) pre[i] = *reinterpret_cast<const u16x8*>(Bg + i * 8);
  }
  for (int ct = 0; ct < 16; ++ct) {
#pragma unroll
    for (int i = 0; i < 4; ++i)
      *lds_gk<256>(Bs, brow, bsub * 32 + i * 8) = pre[i];
    __syncthreads();
    if (ct < 15) {
      const unsigned short* Bg = BT + (size_t)((ct + 1) * 32 + brow) * 256 + bsub * 32;
#pragma unroll
      for (int i = 0; i < 4; ++i) pre[i] = *reinterpret_cast<const u16x8*>(Bg + i * 8);
    }
    f32x4 acc[2];
    acc[0] = (f32x4){0.f, 0.f, 0.f, 0.f};
    acc[1] = (f32x4){0.f, 0.f, 0.f, 0.f};
#pragma unroll
    for (int k = 0; k < 8; ++k) {
      bf16x8 a0 = *reinterpret_cast<bf16x8*>(lds_gk<256>(As, wr * 32 + l16, k * 32 + quad * 8));
      bf16x8 a1 = *reinterpret_cast<bf16x8*>(lds_gk<256>(As, wr * 32 + 16 + l16, k * 32 + quad * 8));
      bf16x8 b0 = *reinterpret_cast<bf16x8*>(lds_gk<256>(Bs, wc * 16 + l16, k * 32 + quad * 8));
      acc[0] = __builtin_amdgcn_mfma_f32_16x16x32_bf16(a0, b0, acc[0], 0, 0, 0);
      acc[1] = __builtin_amdgcn_mfma_f32_16x16x32_bf16(a1, b0, acc[1], 0, 0, 0);
    }
#pragma unroll
    for (int i = 0; i < 2; ++i)
#pragma unroll
      for (int r = 0; r < 4; ++r) {
        int rw = bm + wr * 32 + i * 16 + quad * 4 + r;
        int col = ct * 32 + wc * 16 + l16;
        KVb[(size_t)rw * 512 + col] = f2b(acc[i][r]);
      }
    __syncthreads();
  }
}

// ---- gemm64 body: 64x64 tile, 10.2KB LDS, k-step register prefetch --------
template <bool A_FP32, bool HAS_BIAS, bool DO_GELU, bool HAS_RESID, bool STORE_F32>
__device__ __forceinline__ void gemm64_body(
    char* smem, const void* Ap, const unsigned short* BT, int N, int K,
    const float* bias, const float* resid, float* outF, unsigned short* outB,
    int bm, int bn, int t) {
  unsigned short (*As)[40] = (unsigned short(*)[40])smem;
  unsigned short (*Bs)[40] = (unsigned short(*)[40])(smem + 5120);
  int w = t >> 6, lane = t & 63;
  int wr = w >> 1, wc = w & 1;
  int quad = lane >> 4, l16 = lane & 15;
  int row = t >> 2, chunk = t & 3;

  const float* AgF = (const float*)Ap + (size_t)(bm + row) * K + chunk * 8;
  const unsigned short* AgB = (const unsigned short*)Ap + (size_t)(bm + row) * K + chunk * 8;
  const unsigned short* Bg = BT + (size_t)(bn + row) * K + chunk * 8;

  float4 pf0, pf1;
  u16x8 pa, pb;
  if (A_FP32) { pf0 = *(const float4*)AgF; pf1 = *(const float4*)(AgF + 4); }
  else        { pa = *(const u16x8*)AgB; }
  pb = *(const u16x8*)Bg;

  f32x4 acc[2][2];
#pragma unroll
  for (int i = 0; i < 2; ++i)
#pragma unroll
    for (int j = 0; j < 2; ++j) acc[i][j] = (f32x4){0.f, 0.f, 0.f, 0.f};

  for (int k0 = 0; k0 < K; k0 += 32) {
    u16x8 ua;
    if (A_FP32) {
      ua[0] = f2b(pf0.x); ua[1] = f2b(pf0.y); ua[2] = f2b(pf0.z); ua[3] = f2b(pf0.w);
      ua[4] = f2b(pf1.x); ua[5] = f2b(pf1.y); ua[6] = f2b(pf1.z); ua[7] = f2b(pf1.w);
    } else {
      ua = pa;
    }
    *reinterpret_cast<u16x8*>(&As[row][chunk * 8]) = ua;
    *reinterpret_cast<u16x8*>(&Bs[row][chunk * 8]) = pb;
    __syncthreads();
    if (k0 + 32 < K) {
      if (A_FP32) { pf0 = *(const float4*)(AgF + k0 + 32); pf1 = *(const float4*)(AgF + k0 + 36); }
      else        { pa = *(const u16x8*)(AgB + k0 + 32); }
      pb = *(const u16x8*)(Bg + k0 + 32);
    }
    bf16x8 a0 = *reinterpret_cast<const bf16x8*>(&As[wr * 32 + l16][quad * 8]);
    bf16x8 a1 = *reinterpret_cast<const bf16x8*>(&As[wr * 32 + 16 + l16][quad * 8]);
    bf16x8 b0 = *reinterpret_cast<const bf16x8*>(&Bs[wc * 32 + l16][quad * 8]);
    bf16x8 b1 = *reinterpret_cast<const bf16x8*>(&Bs[wc * 32 + 16 + l16][quad * 8]);
    acc[0][0] = __builtin_amdgcn_mfma_f32_16x16x32_bf16(a0, b0, acc[0][0], 0, 0, 0);
    acc[0][1] = __builtin_amdgcn_mfma_f32_16x16x32_bf16(a0, b1, acc[0][1], 0, 0, 0);
    acc[1][0] = __builtin_amdgcn_mfma_f32_16x16x32_bf16(a1, b0, acc[1][0], 0, 0, 0);
    acc[1][1] = __builtin_amdgcn_mfma_f32_16x16x32_bf16(a1, b1, acc[1][1], 0, 0, 0);
    __syncthreads();
  }

#pragma unroll
  for (int i = 0; i < 2; ++i)
#pragma unroll
    for (int j = 0; j < 2; ++j) {
      int col = bn + wc * 32 + j * 16 + l16;
      float bv = HAS_BIAS ? bias[col] : 0.f;
#pragma unroll
      for (int r = 0; r < 4; ++r) {
        int rw = bm + wr * 32 + i * 16 + quad * 4 + r;
        float v = acc[i][j][r] + bv;
        if (DO_GELU) v = gelu_f(v);
        if (HAS_RESID) v += resid[(size_t)rw * N + col];
        if (STORE_F32) outF[(size_t)rw * N + col] = v;
        else outB[(size_t)rw * N + col] = f2b(v);
      }
    }
}

// ---- geo mega body: stats -> MLP (acc[32], ILP-4 k-loop) -> Gf GEMM -------
// smem layout: [0,3072) rs f32[64][12]; [3072,19456) geo bf16 swizzled [64][128];
// [19456,52224) h1 f32[64][128]  (aliased by Bs bf16[64][128] in phase 3).
// The phase-2 k-loop previously issued ONE scalar Gw2 load per iteration on
// the critical path (128 x ~200cy serial = the geo-straggler that pins all of
// fused_stage2). Restructured: groups of 4 k's, 4 independent Gw2 loads
// issued up front + float4 LDS reads of h1 -> load chain /4. Same FMA order.
__device__ __forceinline__ void geo_body(
    char* smem, const float* qpos, const float* spos, const int* offs,
    const int* s_idx, const float* Gw1, const float* Gb1,
    const float* Gw2, const float* Gb2, const unsigned short* WgT,
    unsigned short* Gf_b, int qb, int t) {
  float (*rs)[12] = (float(*)[12])smem;
  unsigned short* geoL = (unsigned short*)(smem + 3072);
  float (*h1)[128] = (float(*)[128])(smem + 19456);
  unsigned short* Bs = (unsigned short*)(smem + 19456);

  // ---- phase 1: stats (4 lanes per query) ----
  {
    int q = qb + (t >> 2);
    int sub = t & 3;
    int e0 = offs[q], e1 = offs[q + 1];
    float qx = qpos[q * 3 + 0], qy = qpos[q * 3 + 1], qz = qpos[q * 3 + 2];
    float cnt = 0.f, sx = 0.f, sy = 0.f, sz = 0.f, sxx = 0.f, syy = 0.f, szz = 0.f;
    float mnx = 1e30f, mny = 1e30f, mnz = 1e30f, mxx = -1e30f, mxy = -1e30f, mxz = -1e30f;
    for (int e = e0 + sub; e < e1; e += 4) {
      int s = s_idx[e];
      float rx = spos[s * 3 + 0] - qx;
      float ry = spos[s * 3 + 1] - qy;
      float rz = spos[s * 3 + 2] - qz;
      cnt += 1.f;
      sx += rx; sy += ry; sz += rz;
      sxx += rx * rx; syy += ry * ry; szz += rz * rz;
      mnx = fminf(mnx, rx); mny = fminf(mny, ry); mnz = fminf(mnz, rz);
      mxx = fmaxf(mxx, rx); mxy = fmaxf(mxy, ry); mxz = fmaxf(mxz, rz);
    }
#pragma unroll
    for (int msk = 1; msk <= 2; msk <<= 1) {
      cnt += __shfl_xor(cnt, msk);
      sx += __shfl_xor(sx, msk); sy += __shfl_xor(sy, msk); sz += __shfl_xor(sz, msk);
      sxx += __shfl_xor(sxx, msk); syy += __shfl_xor(syy, msk); szz += __shfl_xor(szz, msk);
      mnx = fminf(mnx, __shfl_xor(mnx, msk));
      mny = fminf(mny, __shfl_xor(mny, msk));
      mnz = fminf(mnz, __shfl_xor(mnz, msk));
      mxx = fmaxf(mxx, __shfl_xor(mxx, msk));
      mxy = fmaxf(mxy, __shfl_xor(mxy, msk));
      mxz = fmaxf(mxz, __shfl_xor(mxz, msk));
    }
    if (sub == 0) {
      int qq = t >> 2;
      float c = fmaxf(cnt, 1.f);
      float mx_ = sx / c, my_ = sy / c, mz_ = sz / c;
      float vx = fmaxf(sxx / c - mx_ * mx_, 0.f);
      float vy = fmaxf(syy / c - my_ * my_, 0.f);
      float vz = fmaxf(szz / c - mz_ * mz_, 0.f);
      rs[qq][0] = mx_; rs[qq][1] = my_; rs[qq][2] = mz_;
      rs[qq][3] = sqrtf(vx); rs[qq][4] = sqrtf(vy); rs[qq][5] = sqrtf(vz);
      rs[qq][6] = fminf(fmaxf(mnx, -100.f), 100.f);
      rs[qq][7] = fminf(fmaxf(mny, -100.f), 100.f);
      rs[qq][8] = fminf(fmaxf(mnz, -100.f), 100.f);
      rs[qq][9] = fminf(fmaxf(mxx, -100.f), 100.f);
      rs[qq][10] = fminf(fmaxf(mxy, -100.f), 100.f);
      rs[qq][11] = fminf(fmaxf(mxz, -100.f), 100.f);
    }
  }
  __syncthreads();

  // ---- phase 2: MLP. thread = (dim j, query-group grp of 32) ----
  {
    int j = t & 127;
    int grp = t >> 7;
    int qbase = grp * 32;
    float acc[32];
    float b1 = Gb1[j];
#pragma unroll
    for (int qq = 0; qq < 32; ++qq) acc[qq] = b1;
#pragma unroll
    for (int i = 0; i < 12; ++i) {
      float w = Gw1[i * GEON + j];
#pragma unroll
      for (int qq = 0; qq < 32; ++qq) acc[qq] += rs[qbase + qq][i] * w;
    }
#pragma unroll
    for (int qq = 0; qq < 32; ++qq) h1[qbase + qq][j] = gelu_f(acc[qq]);
    __syncthreads();
    float b2 = Gb2[j];
    float acc2[32];
#pragma unroll
    for (int qq = 0; qq < 32; ++qq) acc2[qq] = b2;
    // ILP-4: 4 independent Gw2 loads per group + float4 LDS reads of h1.
    for (int k = 0; k < 128; k += 4) {
      float w0 = Gw2[(k + 0) * GEON + j];
      float w1 = Gw2[(k + 1) * GEON + j];
      float w2 = Gw2[(k + 2) * GEON + j];
      float w3 = Gw2[(k + 3) * GEON + j];
#pragma unroll
      for (int qq = 0; qq < 32; ++qq) {
        float4 hv = *reinterpret_cast<const float4*>(&h1[qbase + qq][k]);
        acc2[qq] += hv.x * w0;
        acc2[qq] += hv.y * w1;
        acc2[qq] += hv.z * w2;
        acc2[qq] += hv.w * w3;
      }
    }
#pragma unroll
    for (int qq = 0; qq < 32; ++qq)
      *lds_gs128(geoL, qbase + qq, j) = f2b(gelu_f(acc2[qq]));
  }
  __syncthreads();   // geo visible; h1 dead -> Bs may overwrite

  // ---- phase 3: Gf[qb..qb+63, 0..255] = geo @ Wg via MFMA ----
  {
    int w = t >> 6, lane = t & 63;
    int wr = w >> 1, wc = w & 1;
    int quad = lane >> 4, l16 = lane & 15;
    int row = t >> 2, sub = t & 3;
    for (int ct = 0; ct < 4; ++ct) {
      int bn = ct * 64;
      {
        const unsigned short* Bg = WgT + (size_t)(bn + row) * 128 + sub * 32;
#pragma unroll
        for (int i = 0; i < 4; ++i)
          *lds_gk<128>(Bs, row, sub * 32 + i * 8) = *reinterpret_cast<const u16x8*>(Bg + i * 8);
      }
      __syncthreads();
      f32x4 acc[2][2];
#pragma unroll
      for (int i = 0; i < 2; ++i)
#pragma unroll
        for (int j = 0; j < 2; ++j) acc[i][j] = (f32x4){0.f, 0.f, 0.f, 0.f};
#pragma unroll
      for (int k = 0; k < 4; ++k) {
        bf16x8 a0 = *reinterpret_cast<bf16x8*>(lds_gk<128>(geoL, wr * 32 + l16, k * 32 + quad * 8));
        bf16x8 a1 = *reinterpret_cast<bf16x8*>(lds_gk<128>(geoL, wr * 32 + 16 + l16, k * 32 + quad * 8));
        bf16x8 b0 = *reinterpret_cast<bf16x8*>(lds_gk<128>(Bs, wc * 32 + l16, k * 32 + quad * 8));
        bf16x8 b1 = *reinterpret_cast<bf16x8*>(lds_gk<128>(Bs, wc * 32 + 16 + l16, k * 32 + quad * 8));
        acc[0][0] = __builtin_amdgcn_mfma_f32_16x16x32_bf16(a0, b0, acc[0][0], 0, 0, 0);
        acc[0][1] = __builtin_amdgcn_mfma_f32_16x16x32_bf16(a0, b1, acc[0][1], 0, 0, 0);
        acc[1][0] = __builtin_amdgcn_mfma_f32_16x16x32_bf16(a1, b0, acc[1][0], 0, 0, 0);
        acc[1][1] = __builtin_amdgcn_mfma_f32_16x16x32_bf16(a1, b1, acc[1][1], 0, 0, 0);
      }
#pragma unroll
      for (int i = 0; i < 2; ++i)
#pragma unroll
        for (int j = 0; j < 2; ++j) {
          int col = bn + wc * 32 + j * 16 + l16;
#pragma unroll
          for (int r = 0; r < 4; ++r) {
            int rw = qb + wr * 32 + i * 16 + quad * 4 + r;
            Gf_b[(size_t)rw * 256 + col] = f2b(acc[i][j][r]);
          }
        }
      __syncthreads();
    }
  }
}

// ================= L2: fused stage 2 = geo-mega + kv + Qf ==================
__global__ __launch_bounds__(256) void fused_stage2(
    const float* qpos, const float* spos, const int* offs, const int* s_idx,
    const float* Gw1, const float* Gb1, const float* Gw2, const float* Gb2,
    const unsigned short* WgT, unsigned short* Gf_b,
    const float* support_feats, const unsigned short* WkvT, unsigned short* KVb,
    const unsigned short* qt_b, const unsigned short* WqT, unsigned short* Qb) {
  __shared__ __align__(16) char smem[52224];
  int b = blockIdx.x;
  int t = threadIdx.x;
  if (b < 128) {
    geo_body(smem, qpos, spos, offs, s_idx, Gw1, Gb1, Gw2, Gb2, WgT, Gf_b, b * 64, t);
  } else if (b < 640) {
    kv_body(smem, support_feats, WkvT, KVb, (b - 128) * 64, t);
  } else {
    int bb = b - 640;
    int bm = (bb & 127) * 64, bn = (bb >> 7) * 64;
    gemm64_body<false, false, false, false, false>(
        smem, qt_b, WqT, DN, 256, nullptr, nullptr, nullptr, Qb, bm, bn, t);
  }
}

// ---------------- standalone gemm64 wrapper (Wo, FFN1, FFN2) ---------------
template <bool A_FP32, bool HAS_BIAS, bool DO_GELU, bool HAS_RESID, bool STORE_F32>
__global__ __launch_bounds__(256) void gemm64(
    const void* Ap, const unsigned short* BT, int N, int K,
    const float* bias, const float* resid, float* outF, unsigned short* outB) {
  __shared__ __align__(16) char smem[10240];
  gemm64_body<A_FP32, HAS_BIAS, DO_GELU, HAS_RESID, STORE_F32>(
      smem, Ap, BT, N, K, bias, resid, outF, outB,
      blockIdx.x * 64, blockIdx.y * 64, threadIdx.x);
}

// ---------------- edge attention: one wave/query, 4 edges per iteration ----
__global__ __launch_bounds__(256) void attn_edge_kernel(
    const unsigned short* Qb, const unsigned short* Gfb, const unsigned short* KVb,
    const int* s_idx, const int* offs, const float* log_tau, unsigned short* attn_b) {
  int q = blockIdx.x * 4 + (threadIdx.x >> 6);
  int lane = threadIdx.x & 63;
  int slot = lane >> 4;
  int sl = lane & 15;
  int d0 = sl * 16;
  int e0 = offs[q], e1 = offs[q + 1];
  float invs = expf(-log_tau[0]) * 0.17677669529663687f;  // 1/(sqrt(32)*tau)
  u16x8 qu0 = *(const u16x8*)(Qb + (size_t)q * DN + d0);
  u16x8 qu1 = *(const u16x8*)(Qb + (size_t)q * DN + d0 + 8);
  u16x8 gu0 = *(const u16x8*)(Gfb + (size_t)q * DN + d0);
  u16x8 gu1 = *(const u16x8*)(Gfb + (size_t)q * DN + d0 + 8);
  float qf[16], gf[16];
#pragma unroll
  for (int j = 0; j < 8; ++j) {
    qf[j] = b2f(qu0[j]) * invs; qf[j + 8] = b2f(qu1[j]) * invs;
    gf[j] = b2f(gu0[j]);        gf[j + 8] = b2f(gu1[j]);
  }
  const float NEG = -1e30f;
  float m = -INFINITY, l = 0.f;
  float a[16];
#pragma unroll
  for (int j = 0; j < 16; ++j) a[j] = 0.f;
  for (int e = e0; e < e1; e += 4) {
    int ee = e + slot;
    bool valid = ee < e1;
    int s = s_idx[valid ? ee : (e1 - 1)];
    const unsigned short* kr = KVb + (size_t)s * 512 + d0;
    u16x8 ku0 = *(const u16x8*)kr;
    u16x8 ku1 = *(const u16x8*)(kr + 8);
    u16x8 vu0 = *(const u16x8*)(kr + 256);
    u16x8 vu1 = *(const u16x8*)(kr + 264);
    float p = 0.f;
#pragma unroll
    for (int j = 0; j < 8; ++j) {
      p += qf[j] * b2f(ku0[j]);
      p += qf[j + 8] * b2f(ku1[j]);
    }
    p += __shfl_xor(p, 1);
    if (!valid) p = -INFINITY;
    float mnew = fmaxf(m, p);
    float sc = (m > NEG) ? __expf(m - mnew) : 0.f;
    float we = valid ? __expf(p - mnew) : 0.f;
    l = l * sc + we;
#pragma unroll
    for (int j = 0; j < 8; ++j) {
      a[j] = a[j] * sc + we * b2f(vu0[j]);
      a[j + 8] = a[j + 8] * sc + we * b2f(vu1[j]);
    }
    m = mnew;
  }
#pragma unroll
  for (int msk = 16; msk <= 32; msk <<= 1) {
    float om = __shfl_xor(m, msk);
    float ol = __shfl_xor(l, msk);
    float M2 = fmaxf(m, om);
    float ws = (m > NEG) ? __expf(m - M2) : 0.f;
    float wo = (om > NEG) ? __expf(om - M2) : 0.f;
    l = l * ws + ol * wo;
#pragma unroll
    for (int j = 0; j < 16; ++j) {
      float oa = __shfl_xor(a[j], msk);
      a[j] = a[j] * ws + oa * wo;
    }
    m = M2;
  }
  float M = fmaxf(m, 0.f);
  float em = (m > NEG) ? __expf(m - M) : 0.f;
  float denom = fmaxf(l * em, 1e-8f);
  float f = em / denom;
  float sa = l * f;              // = sum(alpha)
  if (slot == 0) {
    u16x8 o0, o1;
#pragma unroll
    for (int j = 0; j < 8; ++j) {
      o0[j] = f2b(a[j] * f + gf[j] * sa);
      o1[j] = f2b(a[j + 8] * f + gf[j + 8] * sa);
    }
    *(u16x8*)(attn_b + (size_t)q * DN + d0) = o0;
    *(u16x8*)(attn_b + (size_t)q * DN + d0 + 8) = o1;
  }
}

extern "C" void kernel_launch(void* const* d_in, const int* in_sizes, int n_in,
                              void* d_out, int out_size, void* d_ws, size_t ws_size,
                              hipStream_t stream) {
  const float* query_tokens  = (const float*)d_in[0];
  const float* query_pos     = (const float*)d_in[1];
  const float* support_feats = (const float*)d_in[2];
  const float* support_pos   = (const float*)d_in[3];
  const float* Wq  = (const float*)d_in[4];
  const float* Wk  = (const float*)d_in[5];
  const float* Wv  = (const float*)d_in[6];
  const float* Wg  = (const float*)d_in[7];
  const float* Wo  = (const float*)d_in[8];
  const float* bo  = (const float*)d_in[9];
  const float* log_tau = (const float*)d_in[10];
  const float* ln1_g = (const float*)d_in[11];
  const float* ln1_b = (const float*)d_in[12];
  const float* ln2_g = (const float*)d_in[13];
  const float* ln2_b = (const float*)d_in[14];
  const float* Wf1 = (const float*)d_in[15];
  const float* bf1 = (const float*)d_in[16];
  const float* Wf2 = (const float*)d_in[17];
  const float* bf2 = (const float*)d_in[18];
  const float* Gw1 = (const float*)d_in[19];
  const float* Gb1 = (const float*)d_in[20];
  const float* Gw2 = (const float*)d_in[21];
  const float* Gb2 = (const float*)d_in[22];
  const int* q_idx = (const int*)d_in[23];
  const int* s_idx = (const int*)d_in[24];
  float* out = (float*)d_out;

  char* ws = (char*)d_ws;
  size_t off = 0;
  auto alloc = [&](size_t bytes) -> void* {
    void* p = ws + off;
    off = (off + bytes + 255) & ~(size_t)255;
    return p;
  };
  unsigned short* WqT  = (unsigned short*)alloc(65536 * 2);
  unsigned short* WkvT = (unsigned short*)alloc(131072 * 2);
  unsigned short* WgT  = (unsigned short*)alloc(32768 * 2);
  unsigned short* WoT  = (unsigned short*)alloc(65536 * 2);
  unsigned short* Wf1T = (unsigned short*)alloc(131072 * 2);
  unsigned short* Wf2T = (unsigned short*)alloc(131072 * 2);
  int* offs            = (int*)alloc((QN + 1) * 4);
  unsigned short* qt_b  = (unsigned short*)alloc((size_t)QN * DN * 2);
  unsigned short* Qb    = (unsigned short*)alloc((size_t)QN * DN * 2);
  unsigned short* Gf_b  = (unsigned short*)alloc((size_t)QN * DN * 2);
  unsigned short* KVb   = (unsigned short*)alloc((size_t)SN * 512 * 2);
  unsigned short* attn_b = (unsigned short*)alloc((size_t)QN * DN * 2);
  float* x1             = (float*)alloc((size_t)QN * DN * 4);
  unsigned short* z_b   = (unsigned short*)alloc((size_t)QN * DN * 2);
  unsigned short* h_b   = (unsigned short*)alloc((size_t)QN * FFNN * 2);

  // L1: weight transpose + segment offsets + LN1  (input-only deps)
  fused_prep<<<2217, 256, 0, stream>>>(Wq, Wk, Wv, Wg, Wo, Wf1, Wf2,
                                       WqT, WkvT, WgT, WoT, Wf1T, Wf2T,
                                       q_idx, offs,
                                       query_tokens, ln1_g, ln1_b, qt_b);
  // L2: geo(stats->MLP->Gf) + KV gemm + Qf gemm  (co-scheduled)
  fused_stage2<<<1152, 256, 0, stream>>>(query_pos, support_pos, offs, s_idx,
                                         Gw1, Gb1, Gw2, Gb2, WgT, Gf_b,
                                         support_feats, WkvT, KVb,
                                         qt_b, WqT, Qb);
  // L3: edge attention -> attn_b bf16
  attn_edge_kernel<<<QN / 4, 256, 0, stream>>>(Qb, Gf_b, KVb, s_idx, offs, log_tau, attn_b);
  // L4: x1 = attn @ Wo + bo + query_tokens, store fp32
  gemm64<false, true, false, true, true><<<dim3(QN / 64, DN / 64), 256, 0, stream>>>(
      attn_b, WoT, DN, 256, bo, query_tokens, x1, nullptr);
  // L5: LN2
  ln_kernel<<<QN / 4, 256, 0, stream>>>(x1, ln2_g, ln2_b, z_b);
  // L6: h = gelu(z @ Wf1 + bf1), store bf16
  gemm64<false, true, true, false, false><<<dim3(QN / 64, FFNN / 64), 256, 0, stream>>>(
      z_b, Wf1T, FFNN, 256, bf1, nullptr, nullptr, h_b);
  // L7: out = h @ Wf2 + bf2 + x1, store fp32 -> d_out
  gemm64<false, true, false, true, true><<<dim3(QN / 64, DN / 64), 256, 0, stream>>>(
      h_b, Wf2T, DN, 512, bf2, x1, out, nullptr);

  (void)in_sizes; (void)n_in; (void)out_size; (void)ws_size;
}